// Round 5
// baseline (331.235 us; speedup 1.0000x reference)
//
#include <hip/hip_runtime.h>
#include <stdint.h>

constexpr int Bsz = 2;
constexpr int Ssz = 2048;
constexpr int Hid = 2048;
constexpr int NHd = 16;
constexpr int Hd  = 128;
constexpr int Mrows = Bsz * Ssz;                 // 4096

typedef __bf16 bf16;
typedef __bf16 bf16x8 __attribute__((ext_vector_type(8)));
typedef __bf16 bf16x4 __attribute__((ext_vector_type(4)));
typedef float  f32x4  __attribute__((ext_vector_type(4)));
typedef float  f32x16 __attribute__((ext_vector_type(16)));

__device__ __forceinline__ void gload_lds16(const bf16* g, bf16* l) {
  __builtin_amdgcn_global_load_lds((const __attribute__((address_space(1))) void*)g,
                                   (__attribute__((address_space(3))) void*)l, 16, 0, 0);
}

__device__ __forceinline__ uint32_t pkbf(bf16 a, bf16 b) {
  union { bf16 hh[2]; uint32_t u; } x;
  x.hh[0] = a; x.hh[1] = b;
  return x.u;
}
__device__ __forceinline__ uint32_t pkff(float a, float b) {
  return pkbf((bf16)a, (bf16)b);
}

// ---------------- f32 -> bf16 bulk convert (4 elems/thread) ----------------
__global__ void k_cvt(const float* __restrict__ in, bf16* __restrict__ out, int n4) {
  int i = blockIdx.x * blockDim.x + threadIdx.x;
  if (i >= n4) return;
  float4 v = ((const float4*)in)[i];
  bf16x4 o = { (bf16)v.x, (bf16)v.y, (bf16)v.z, (bf16)v.w };
  ((bf16x4*)out)[i] = o;
}

// ------------- transpose 4 weights [K][N] f32 -> [N][K] bf16 ---------------
__global__ void k_wtrans(const float* __restrict__ w0, const float* __restrict__ w1,
                         const float* __restrict__ w2, const float* __restrict__ w3,
                         bf16* __restrict__ out) {
  __shared__ float tile[32][33];
  int z = blockIdx.z;
  const float* w = (z == 0) ? w0 : (z == 1) ? w1 : (z == 2) ? w2 : w3;
  bf16* o = out + (size_t)z * Hid * Hid;
  int n0 = blockIdx.x * 32, k0 = blockIdx.y * 32;
  int tx = threadIdx.x, ty = threadIdx.y;
#pragma unroll
  for (int i = 0; i < 4; i++)
    tile[ty + i * 8][tx] = w[(size_t)(k0 + ty + i * 8) * Hid + n0 + tx];
  __syncthreads();
#pragma unroll
  for (int i = 0; i < 4; i++)
    o[(size_t)(n0 + ty + i * 8) * Hid + k0 + tx] = (bf16)tile[tx][ty + i * 8];
}

// ---- swizzled-LDS fragment read: element (row,k) lives at byte
//      row*128 + (((k>>3) ^ (row&7))<<4) + (k&7)*2
__device__ __forceinline__ bf16x8 rdfrag(const bf16* t, int row, int kslot) {
  return *(const bf16x8*)((const char*)t + row * 128 + (((kslot ^ (row & 7)) & 7) << 4));
}

// ---- stage NB 1KB-blocks of a [rows][64] bf16 K-slice into linear LDS,
//      source pre-inverse-swizzled so reads use rdfrag (rule #21)
template <int NB>
__device__ __forceinline__ void stageN(const bf16* g, bf16* l, int w, int lane) {
  const int rsub = lane >> 3;
  const int slot = (lane & 7) ^ rsub;
#pragma unroll
  for (int j = 0; j < NB; ++j) {
    const int blk = w * NB + j;
    gload_lds16(g + (size_t)(blk * 8 + rsub) * Hid + slot * 8, l + blk * 512);
  }
}

#define PH_SYNC()                                      \
  __builtin_amdgcn_s_barrier();                        \
  asm volatile("s_waitcnt lgkmcnt(0)" ::: "memory");   \
  __builtin_amdgcn_sched_barrier(0);

// ---- m201-geometry bf16 GEMM: 256x256 tile, BK=64, 8 waves (2m x 4n),
//      per-wave 128x64, 4 phases/K-tile x 16 MFMA, dbuf 128 KB LDS.
//      Tile t+1's 8 loads issued in phases 0-1 of tile t (>=2 phases of
//      prefetch distance), single completed-wait at the tile boundary.
// MODE 0: fused QKV (N=6144): C = A@W^T + bias -> bf16 scatter [b][h][s][hd],
//         K output scaled by kScale*log2e (softmax in log2 domain)
// MODE 1: C = A@W^T -> f32 row-major (output projection)
template <int MODE, int CHM, int CHN>
__global__ __launch_bounds__(512, 2) void k_gemm(const bf16* __restrict__ A,
                                                 const bf16* __restrict__ Bt,
                                                 const float* __restrict__ biasq,
                                                 const float* __restrict__ biask,
                                                 const float* __restrict__ biasv,
                                                 bf16* __restrict__ Qo, bf16* __restrict__ Ko,
                                                 bf16* __restrict__ Vo, float* __restrict__ Fo) {
  constexpr int KK = Hid;
  constexpr int NT = KK / 64;
  __shared__ bf16 smA[2][256 * 64];   // 64 KB
  __shared__ bf16 smB[2][256 * 64];   // 64 KB
  // T1: 2D chunk per XCD (hw dispatch id % 8 -> XCD), bijective
  const int hw = blockIdx.y * gridDim.x + blockIdx.x;
  const int chunk = hw & 7, within = hw >> 3;
  const int chunk_rows = gridDim.y / CHM;
  const int cr = chunk % chunk_rows, cc = chunk / chunk_rows;
  const int mt = cr * CHM + within % CHM;
  const int nt = cc * CHN + within / CHM;
  const int m0 = mt * 256, n0 = nt * 256;
  const int tid = threadIdx.x, lane = tid & 63, w = tid >> 6;
  const int wm = w >> 2, wn = w & 3;
  const int frow = lane & 15, a4 = lane >> 4;
  const bf16* Ag = A + (size_t)m0 * KK;
  const bf16* Bg = Bt + (size_t)n0 * KK;
  f32x4 acc[8][4] = {};
  // prologue: tile 0 -> buf0
  stageN<4>(Ag, smA[0], w, lane);
  stageN<4>(Bg, smB[0], w, lane);
  asm volatile("s_waitcnt vmcnt(0)" ::: "memory");
  __builtin_amdgcn_s_barrier();
  for (int kt = 0; kt < NT; ++kt) {
    const bf16* At  = smA[kt & 1];
    const bf16* Btl = smB[kt & 1];
    bf16* As2 = smA[(kt + 1) & 1];
    bf16* Bs2 = smB[(kt + 1) & 1];
    const int kn = (kt + 1 < NT ? kt + 1 : kt) * 64;   // tail: harmless re-load
    // B fragments for the whole K-tile (held in regs across phases)
    bf16x8 bfr[4][2];
#pragma unroll
    for (int nf = 0; nf < 4; ++nf)
#pragma unroll
      for (int kk = 0; kk < 2; ++kk)
        bfr[nf][kk] = rdfrag(Btl, wn * 64 + nf * 16 + frow, kk * 4 + a4);
#pragma unroll
    for (int ph = 0; ph < 4; ++ph) {
      bf16x8 af[2][2];
#pragma unroll
      for (int i = 0; i < 2; ++i)
#pragma unroll
        for (int kk = 0; kk < 2; ++kk)
          af[i][kk] = rdfrag(At, wm * 128 + (ph * 2 + i) * 16 + frow, kk * 4 + a4);
      if (ph == 0) stageN<4>(Ag + kn, As2, w, lane);   // A(t+1): 4 loads
      if (ph == 1) stageN<4>(Bg + kn, Bs2, w, lane);   // B(t+1): 4 loads
      PH_SYNC();
      __builtin_amdgcn_s_setprio(1);
#pragma unroll
      for (int i = 0; i < 2; ++i)
#pragma unroll
        for (int nf = 0; nf < 4; ++nf)
#pragma unroll
          for (int kk = 0; kk < 2; ++kk)
            acc[ph * 2 + i][nf] = __builtin_amdgcn_mfma_f32_16x16x32_bf16(
                af[i][kk], bfr[nf][kk], acc[ph * 2 + i][nf], 0, 0, 0);
      __builtin_amdgcn_s_setprio(0);
      if (ph == 3) {  // tile t+1 complete (its loads are >=2 phases old)
        asm volatile("s_waitcnt vmcnt(0)" ::: "memory");
        __builtin_amdgcn_sched_barrier(0);
      }
      __builtin_amdgcn_s_barrier();
    }
  }
  // ---- epilogue: per-wave region rows [m0+wm*128,+128) x cols [n0+wn*64,+64)
  if (MODE == 0) {
    const int z = n0 >> 11;                      // BN=256 divides 2048: single z
    const float* bias = (z == 0) ? biasq : (z == 1) ? biask : biasv;
    bf16* o = (z == 0) ? Qo : (z == 1) ? Ko : Vo;
    const float oscale = (z == 1) ? (float)(0.08838834764831845 * 1.4426950408889634) : 1.0f;
#pragma unroll
    for (int nf = 0; nf < 4; ++nf) {
      const int col = n0 + wn * 64 + nf * 16 + frow;
      const float bb_ = bias[col & 2047];
      const int h = (col >> 7) & 15, hd = col & (Hd - 1);
#pragma unroll
      for (int mf = 0; mf < 8; ++mf) {
#pragma unroll
        for (int r = 0; r < 4; ++r) {
          const int row = m0 + wm * 128 + mf * 16 + a4 * 4 + r;
          const int bb = row >> 11, ss = row & (Ssz - 1);
          o[(((size_t)bb * NHd + h) * Ssz + ss) * Hd + hd] = (bf16)((acc[mf][nf][r] + bb_) * oscale);
        }
      }
    }
  } else {
#pragma unroll
    for (int mf = 0; mf < 8; ++mf)
#pragma unroll
      for (int nf = 0; nf < 4; ++nf) {
        const int col = n0 + wn * 64 + nf * 16 + frow;
#pragma unroll
        for (int r = 0; r < 4; ++r) {
          const int row = m0 + wm * 128 + mf * 16 + a4 * 4 + r;
          Fo[(size_t)row * Hid + col] = acc[mf][nf][r];
        }
      }
  }
}

// ---------------- RoPE (neox) on Q and K in place --------------------------
__global__ void k_rope(bf16* __restrict__ Q, bf16* __restrict__ Kk, const int* __restrict__ pos) {
  const int idx = blockIdx.x * 256 + threadIdx.x;   // (bh, s, i) i fastest
  const int i = idx & 63;
  const int s = (idx >> 6) & (Ssz - 1);
  const int bh = idx >> 17;
  const int b = bh >> 4;
  const float p = (float)pos[b * Ssz + s];
  const float f = p * exp2f(-(float)i * 0.20762050593046014f); // log2(1e4)/64
  float sn, cs;
  sincosf(f, &sn, &cs);
  const size_t base = ((size_t)bh * Ssz + s) * Hd;
  float x1 = (float)Q[base + i], x2 = (float)Q[base + i + 64];
  Q[base + i]      = (bf16)(x1 * cs - x2 * sn);
  Q[base + i + 64] = (bf16)(x2 * cs + x1 * sn);
  x1 = (float)Kk[base + i]; x2 = (float)Kk[base + i + 64];
  Kk[base + i]      = (bf16)(x1 * cs - x2 * sn);
  Kk[base + i + 64] = (bf16)(x2 * cs + x1 * sn);
}

// ------------- causal flash attention, swapped-QK, 32x32x16 MFMA -----------
// T14 async-stage: K(t+1) gload_lds + V(t+1)->reg issued before compute(t);
// double-buffered K/V LDS; counted vmcnt(8) before the compute barrier.
__global__ __launch_bounds__(256, 2) void k_attn(const bf16* __restrict__ Qg,
                                                 const bf16* __restrict__ Kg,
                                                 const bf16* __restrict__ Vg,
                                                 bf16* __restrict__ AO) {
  const int bh = blockIdx.y;
  int qc = blockIdx.x;
  if (bh & 1) qc = 15 - qc;            // causal load balance across co-resident blocks
  const int tid = threadIdx.x, lane = tid & 63, w = tid >> 6;
  const int l31 = lane & 31, h = lane >> 5;
  __shared__ bf16 Ks[2][64 * 128];     // XOR-swizzled contents (16B granule by row&7)
  __shared__ bf16 Vt[2][128 * 72];     // V^T: [hd][key], pad 72, swz by (hd>>3)&7
  const size_t hbase = (size_t)bh * Ssz * Hd;
  const int q0 = qc * 128 + w * 32;    // wave's first query row
  bf16x8 qf[8];
  {
    const bf16* qp = Qg + hbase + (size_t)(q0 + l31) * Hd + h * 8;
#pragma unroll
    for (int c = 0; c < 8; c++) qf[c] = *(const bf16x8*)(qp + c * 16);
  }
  float m = -1e30f, lsum = 0.f;
  f32x16 o[4] = {};
  const int NT = 2 * (qc + 1);
  const int r4  = (tid >> 4) << 2;     // V staging: this thread's 4 keys
  const int hd0 = (tid & 15) << 3;     //   and 8 hd values
  bf16x8 vv[4];
  // ---- prologue: issue tile-0 V->reg then K->LDS
#pragma unroll
  for (int p = 0; p < 4; p++)
    vv[p] = *(const bf16x8*)(Vg + hbase + (size_t)(r4 + p) * Hd + hd0);
  __builtin_amdgcn_sched_barrier(0);
#pragma unroll
  for (int i = 0; i < 4; i++) {
    const int db  = (w * 4 + i) * 1024 + (lane << 4);
    const int row = db >> 8;
    const int cb  = (db & 255) ^ ((row & 7) << 4);
    gload_lds16(Kg + hbase + row * Hd + (cb >> 1), Ks[0] + (w * 4 + i) * 512);
  }
  for (int t = 0; t < NT; ++t) {
    const int kv0 = t * 64;
    const int cur = t & 1;
    // ---- V(t) regs ready (oldest 4 of <=8 outstanding); write V(t) -> LDS
    asm volatile("s_waitcnt vmcnt(4)" ::: "memory");
#pragma unroll
    for (int j = 0; j < 8; j++) {
      uint2 wv;
      wv.x = pkbf(vv[0][j], vv[1][j]);
      wv.y = pkbf(vv[2][j], vv[3][j]);
      const int hd = hd0 + j;
      const int cb = (r4 * 2) ^ (((hd >> 3) & 7) << 4);
      *(uint2*)((char*)(Vt[cur]) + hd * 144 + cb) = wv;
    }
    // ---- issue tile t+1 (redundant re-issue of t on last iter)
    const int tn = (t + 1 < NT) ? t + 1 : t;
    const size_t nb = (size_t)tn * 64;
#pragma unroll
    for (int p = 0; p < 4; p++)
      vv[p] = *(const bf16x8*)(Vg + hbase + (nb + r4 + p) * Hd + hd0);
    __builtin_amdgcn_sched_barrier(0);
#pragma unroll
    for (int i = 0; i < 4; i++) {
      const int db  = (w * 4 + i) * 1024 + (lane << 4);
      const int row = db >> 8;
      const int cb  = (db & 255) ^ ((row & 7) << 4);
      gload_lds16(Kg + hbase + (nb + row) * Hd + (cb >> 1), Ks[cur ^ 1] + (w * 4 + i) * 512);
    }
    // ---- K(t) in LDS (8 newest = t+1's loads stay in flight); V writes visible
    asm volatile("s_waitcnt vmcnt(8) lgkmcnt(0)" ::: "memory");
    __builtin_amdgcn_sched_barrier(0);
    __builtin_amdgcn_s_barrier();
    if (kv0 <= q0 + 31) {              // wave-uniform: skip fully-masked tiles
      const bf16* KsC = Ks[cur];
      const bf16* VtC = Vt[cur];
      f32x16 s0 = {}, s1 = {};
#pragma unroll
      for (int c = 0; c < 8; c++) {
        const int cb = (c * 32 + h * 16) ^ ((l31 & 7) << 4);
        bf16x8 k0 = *(const bf16x8*)((const char*)KsC + l31 * 256 + cb);
        bf16x8 k1 = *(const bf16x8*)((const char*)KsC + (32 + l31) * 256 + cb);
        s0 = __builtin_amdgcn_mfma_f32_32x32x16_bf16(k0, qf[c], s0, 0, 0, 0);
        s1 = __builtin_amdgcn_mfma_f32_32x32x16_bf16(k1, qf[c], s1, 0, 0, 0);
      }
      if (kv0 + 63 > q0) {
        const int qg = q0 + l31;
        const int kb = kv0 + 4 * h;
#pragma unroll
        for (int r = 0; r < 16; r++) {
          const int cr = (r & 3) + 8 * (r >> 2);
          if (kb + cr > qg)      s0[r] = -1e30f;
          if (kb + 32 + cr > qg) s1[r] = -1e30f;
        }
      }
      float tm = s0[0];
#pragma unroll
      for (int r = 1; r < 16; r++) tm = fmaxf(tm, s0[r]);
#pragma unroll
      for (int r = 0; r < 16; r++) tm = fmaxf(tm, s1[r]);
      tm = fmaxf(tm, __shfl_xor(tm, 32));
      if (!__all(tm - m <= 8.0f)) {    // defer-max (T13)
        const float mn = fmaxf(m, tm);
        const float rs = exp2f(m - mn);
        m = mn; lsum *= rs;
#pragma unroll
        for (int ct = 0; ct < 4; ct++)
#pragma unroll
          for (int r = 0; r < 16; r++) o[ct][r] *= rs;
      }
      float ps = 0.f;
#pragma unroll
      for (int r = 0; r < 16; r++) { s0[r] = exp2f(s0[r] - m); ps += s0[r]; }
#pragma unroll
      for (int r = 0; r < 16; r++) { s1[r] = exp2f(s1[r] - m); ps += s1[r]; }
      ps += __shfl_xor(ps, 32);
      lsum += ps;
      uint32_t gw[8][2];
#pragma unroll
      for (int g = 0; g < 4; g++) {
        gw[g][0]     = pkff(s0[4 * g], s0[4 * g + 1]);
        gw[g][1]     = pkff(s0[4 * g + 2], s0[4 * g + 3]);
        gw[4 + g][0] = pkff(s1[4 * g], s1[4 * g + 1]);
        gw[4 + g][1] = pkff(s1[4 * g + 2], s1[4 * g + 3]);
      }
#pragma unroll
      for (int kc = 0; kc < 4; kc++) {
        const uint32_t a0 = gw[2 * kc][0], a1 = gw[2 * kc][1];
        const uint32_t b0 = gw[2 * kc + 1][0], b1 = gw[2 * kc + 1][1];
        const uint32_t sd0 = h ? a0 : b0, sd1 = h ? a1 : b1;
        const uint32_t r0 = (uint32_t)__shfl_xor((int)sd0, 32);
        const uint32_t r1 = (uint32_t)__shfl_xor((int)sd1, 32);
        union { uint32_t u[4]; bf16x8 v; } pa;
        pa.u[0] = h ? r0 : a0; pa.u[1] = h ? r1 : a1;
        pa.u[2] = h ? b0 : r0; pa.u[3] = h ? b1 : r1;
#pragma unroll
        for (int ct = 0; ct < 4; ct++) {
          const int row = ct * 32 + l31;
          const int cb = (kc * 32 + h * 16) ^ (((row >> 3) & 7) << 4);
          bf16x8 vf = *(const bf16x8*)((const char*)VtC + row * 144 + cb);
          o[ct] = __builtin_amdgcn_mfma_f32_32x32x16_bf16(pa.v, vf, o[ct], 0, 0, 0);
        }
      }
    }
    __builtin_amdgcn_s_barrier();      // compute done before next tile's writes
  }
  const float linv = 1.0f / lsum;
  float li[16];
#pragma unroll
  for (int r = 0; r < 16; r++)
    li[r] = __shfl(linv, (r & 3) + 8 * (r >> 2) + 4 * h);
  const int b = bh >> 4, hh = bh & 15;
#pragma unroll
  for (int ct = 0; ct < 4; ct++) {
#pragma unroll
    for (int r = 0; r < 16; r++) {
      const int qrow = q0 + (r & 3) + 8 * (r >> 2) + 4 * h;
      AO[((size_t)b * Ssz + qrow) * Hid + hh * Hd + ct * 32 + l31] = (bf16)(o[ct][r] * li[r]);
    }
  }
}

extern "C" void kernel_launch(void* const* d_in, const int* in_sizes, int n_in,
                              void* d_out, int out_size, void* d_ws, size_t ws_size,
                              hipStream_t stream) {
  (void)in_sizes; (void)n_in; (void)out_size; (void)ws_size;
  const float* hidden   = (const float*)d_in[0];
  const int*   positions= (const int*)d_in[1];
  const float* wq = (const float*)d_in[2];
  const float* bq = (const float*)d_in[3];
  const float* wk = (const float*)d_in[4];
  const float* bk = (const float*)d_in[5];
  const float* wv = (const float*)d_in[6];
  const float* bv = (const float*)d_in[7];
  const float* wc = (const float*)d_in[8];
  float* out = (float*)d_out;

  char* ws = (char*)d_ws;
  bf16* WT  = (bf16*)ws;                                               // 4*Hid*Hid bf16 (q,k,v,c)
  bf16* Hbf = (bf16*)(ws + (size_t)4 * Hid * Hid * 2);                 // Mrows*Hid (reused as AO)
  bf16* Qb  = (bf16*)(ws + (size_t)4 * Hid * Hid * 2 + (size_t)Mrows * Hid * 2);
  bf16* Kb  = Qb + (size_t)Mrows * Hid;
  bf16* Vb  = Kb + (size_t)Mrows * Hid;

  k_cvt<<<dim3(Mrows * Hid / 4 / 256), dim3(256), 0, stream>>>(hidden, Hbf, Mrows * Hid / 4);
  k_wtrans<<<dim3(Hid / 32, Hid / 32, 4), dim3(32, 8), 0, stream>>>(wq, wk, wv, wc, WT);
  // fused QKV: N = 6144, grid 24x16 = 384 blocks; XCD chunks 8m x 6n
  k_gemm<0, 8, 6><<<dim3(24, 16), dim3(512), 0, stream>>>(
      Hbf, WT, bq, bk, bv, Qb, Kb, Vb, nullptr);
  k_rope<<<dim3(Bsz * NHd * Ssz * 64 / 256), dim3(256), 0, stream>>>(Qb, Kb, positions);
  k_attn<<<dim3(16, Bsz * NHd), dim3(256), 0, stream>>>(Qb, Kb, Vb, Hbf /*AO*/);
  // output projection: grid 8x16 = 128 blocks; XCD chunks 8m x 2n
  k_gemm<1, 8, 2><<<dim3(8, 16), dim3(512), 0, stream>>>(
      Hbf, WT + (size_t)3 * Hid * Hid, nullptr, nullptr, nullptr,
      nullptr, nullptr, nullptr, out);
}

// Round 6
// 297.984 us; speedup vs baseline: 1.1116x; 1.1116x over previous
//
#include <hip/hip_runtime.h>
#include <stdint.h>

constexpr int Bsz = 2;
constexpr int Ssz = 2048;
constexpr int Hid = 2048;
constexpr int NHd = 16;
constexpr int Hd  = 128;
constexpr int Mrows = Bsz * Ssz;                 // 4096

typedef __bf16 bf16;
typedef __bf16 bf16x8 __attribute__((ext_vector_type(8)));
typedef __bf16 bf16x4 __attribute__((ext_vector_type(4)));
typedef float  f32x4  __attribute__((ext_vector_type(4)));
typedef float  f32x16 __attribute__((ext_vector_type(16)));

__device__ __forceinline__ void gload_lds16(const bf16* g, bf16* l) {
  __builtin_amdgcn_global_load_lds((const __attribute__((address_space(1))) void*)g,
                                   (__attribute__((address_space(3))) void*)l, 16, 0, 0);
}

__device__ __forceinline__ uint32_t pkbf(bf16 a, bf16 b) {
  union { bf16 hh[2]; uint32_t u; } x;
  x.hh[0] = a; x.hh[1] = b;
  return x.u;
}
__device__ __forceinline__ uint32_t pkff(float a, float b) {
  return pkbf((bf16)a, (bf16)b);
}

// ---------------- f32 -> bf16 bulk convert (4 elems/thread) ----------------
__global__ void k_cvt(const float* __restrict__ in, bf16* __restrict__ out, int n4) {
  int i = blockIdx.x * blockDim.x + threadIdx.x;
  if (i >= n4) return;
  float4 v = ((const float4*)in)[i];
  bf16x4 o = { (bf16)v.x, (bf16)v.y, (bf16)v.z, (bf16)v.w };
  ((bf16x4*)out)[i] = o;
}

// ------------- transpose 4 weights [K][N] f32 -> [N][K] bf16 ---------------
__global__ void k_wtrans(const float* __restrict__ w0, const float* __restrict__ w1,
                         const float* __restrict__ w2, const float* __restrict__ w3,
                         bf16* __restrict__ out) {
  __shared__ float tile[32][33];
  int z = blockIdx.z;
  const float* w = (z == 0) ? w0 : (z == 1) ? w1 : (z == 2) ? w2 : w3;
  bf16* o = out + (size_t)z * Hid * Hid;
  int n0 = blockIdx.x * 32, k0 = blockIdx.y * 32;
  int tx = threadIdx.x, ty = threadIdx.y;
#pragma unroll
  for (int i = 0; i < 4; i++)
    tile[ty + i * 8][tx] = w[(size_t)(k0 + ty + i * 8) * Hid + n0 + tx];
  __syncthreads();
#pragma unroll
  for (int i = 0; i < 4; i++)
    o[(size_t)(n0 + ty + i * 8) * Hid + k0 + tx] = (bf16)tile[tx][ty + i * 8];
}

// ---- swizzled-LDS fragment read: element (row,k) lives at byte
//      row*128 + (((k>>3) ^ (row&7))<<4) + (k&7)*2
__device__ __forceinline__ bf16x8 rdfrag(const bf16* t, int row, int kslot) {
  return *(const bf16x8*)((const char*)t + row * 128 + (((kslot ^ (row & 7)) & 7) << 4));
}

// ---- stage a 128-row x 64-col bf16 slice (16 KB) into linear LDS,
//      source pre-inverse-swizzled so reads use rdfrag (rule #21).
//      2 gload_lds per wave (8 waves x 2 x 1KB = 16 KB).
__device__ __forceinline__ void stage_half(const bf16* g, bf16* l, int w, int lane) {
  const int rsub = lane >> 3;
  const int slot = (lane & 7) ^ rsub;
#pragma unroll
  for (int j = 0; j < 2; ++j) {
    const int blk = w * 2 + j;
    gload_lds16(g + (size_t)(blk * 8 + rsub) * Hid + slot * 8, l + blk * 512);
  }
}

#define PH_SYNC()                                      \
  __builtin_amdgcn_s_barrier();                        \
  asm volatile("s_waitcnt lgkmcnt(0)" ::: "memory");   \
  __builtin_amdgcn_sched_barrier(0);

// ---- pipelined bf16 GEMM: 256x128 tile, BK=64, 8 waves (2M x 4N),
//      per-wave 128x32, 4 phases / 2 K-tiles, counted vmcnt(2) boundaries
//      (never drains mid-loop), dbuf 96 KB LDS (even tiles slot0, odd slot1).
// MODE 0: fused QKV (N=6144): C = A@W^T + bias -> bf16 scatter [b][h][s][hd],
//         K output scaled by kScale*log2e (softmax in log2 domain)
// MODE 1: C = A@W^T -> f32 row-major (output projection)
// CHM/CHN: per-XCD chunk dims (in 256-row / 128-col tiles), bijective.
template <int MODE, int CHM, int CHN>
__global__ __launch_bounds__(512, 1) void k_gemm(const bf16* __restrict__ A,
                                                 const bf16* __restrict__ Bt,
                                                 const float* __restrict__ biasq,
                                                 const float* __restrict__ biask,
                                                 const float* __restrict__ biasv,
                                                 bf16* __restrict__ Qo, bf16* __restrict__ Ko,
                                                 bf16* __restrict__ Vo, float* __restrict__ Fo) {
  constexpr int KK = Hid;
  constexpr int NT = KK / 64;          // 32 K-tiles
  __shared__ bf16 smA[2][256 * 64];    // 64 KB
  __shared__ bf16 smB[2][128 * 64];    // 32 KB
  // T1: 2D chunk per XCD (hw dispatch id % 8 -> XCD), bijective
  const int hw = blockIdx.y * gridDim.x + blockIdx.x;
  const int chunk = hw & 7, within = hw >> 3;
  const int chunk_rows = gridDim.y / CHM;
  const int cr = chunk % chunk_rows, cc = chunk / chunk_rows;
  const int mt = cr * CHM + within % CHM;
  const int nt = cc * CHN + within / CHM;
  const int m0 = mt * 256, n0 = nt * 128;
  const int tid = threadIdx.x, lane = tid & 63, w = tid >> 6;
  const int wm = w >> 2, wn = w & 3;
  const int frow = lane & 15, a4 = lane >> 4;
  const bf16* Ag = A + (size_t)m0 * KK;
  const bf16* Bg = Bt + (size_t)n0 * KK;
  f32x4 acc[8][2] = {};
  // ---- prologue: tile0.A0, tile0.A1, tile0.B, tile1.B; complete first 3
  stage_half(Ag,                    smA[0],            w, lane);
  stage_half(Ag + (size_t)128 * KK, smA[0] + 128 * 64, w, lane);
  stage_half(Bg,                    smB[0],            w, lane);
  stage_half(Bg + 64,               smB[1],            w, lane);
  asm volatile("s_waitcnt vmcnt(2)" ::: "memory");
  __builtin_amdgcn_sched_barrier(0);
  __builtin_amdgcn_s_barrier();
  for (int it = 0; it < NT / 2; ++it) {
    const int base = 2 * it;
    const bool has2 = (base + 2) < NT;
    const bool has3 = (base + 3) < NT;
    bf16x8 af[4][2], bfr[2][2];
    // ======== P1: kt0 (slot0) A fr0-3 + B; stage (base+1).A0/A1 -> slot1
#pragma unroll
    for (int f = 0; f < 4; ++f)
#pragma unroll
      for (int kk = 0; kk < 2; ++kk)
        af[f][kk] = rdfrag(smA[0], wm * 128 + f * 16 + frow, kk * 4 + a4);
#pragma unroll
    for (int nf = 0; nf < 2; ++nf)
#pragma unroll
      for (int kk = 0; kk < 2; ++kk)
        bfr[nf][kk] = rdfrag(smB[0], wn * 32 + nf * 16 + frow, kk * 4 + a4);
    {
      const size_t kA1 = (size_t)(base + 1) * 64;
      stage_half(Ag + kA1,                    smA[1],            w, lane);
      stage_half(Ag + (size_t)128 * KK + kA1, smA[1] + 128 * 64, w, lane);
    }
    PH_SYNC();
    __builtin_amdgcn_s_setprio(1);
#pragma unroll
    for (int f = 0; f < 4; ++f)
#pragma unroll
      for (int nf = 0; nf < 2; ++nf)
#pragma unroll
        for (int kk = 0; kk < 2; ++kk)
          acc[f][nf] = __builtin_amdgcn_mfma_f32_16x16x32_bf16(
              af[f][kk], bfr[nf][kk], acc[f][nf], 0, 0, 0);
    __builtin_amdgcn_s_setprio(0);
    __builtin_amdgcn_s_barrier();
    // ======== P2: kt0 A fr4-7; stage (base+2).B -> slot0; W1 = vmcnt(2)
#pragma unroll
    for (int f = 0; f < 4; ++f)
#pragma unroll
      for (int kk = 0; kk < 2; ++kk)
        af[f][kk] = rdfrag(smA[0], wm * 128 + (4 + f) * 16 + frow, kk * 4 + a4);
    if (has2) stage_half(Bg + (size_t)(base + 2) * 64, smB[0], w, lane);
    PH_SYNC();
    __builtin_amdgcn_s_setprio(1);
#pragma unroll
    for (int f = 0; f < 4; ++f)
#pragma unroll
      for (int nf = 0; nf < 2; ++nf)
#pragma unroll
        for (int kk = 0; kk < 2; ++kk)
          acc[4 + f][nf] = __builtin_amdgcn_mfma_f32_16x16x32_bf16(
              af[f][kk], bfr[nf][kk], acc[4 + f][nf], 0, 0, 0);
    __builtin_amdgcn_s_setprio(0);
    if (has2) { asm volatile("s_waitcnt vmcnt(2)" ::: "memory"); }
    else      { asm volatile("s_waitcnt vmcnt(0)" ::: "memory"); }
    __builtin_amdgcn_sched_barrier(0);
    __builtin_amdgcn_s_barrier();
    // ======== P3: kt1 (slot1) A fr0-3 + B; stage (base+2).A0/A1 -> slot0
#pragma unroll
    for (int f = 0; f < 4; ++f)
#pragma unroll
      for (int kk = 0; kk < 2; ++kk)
        af[f][kk] = rdfrag(smA[1], wm * 128 + f * 16 + frow, kk * 4 + a4);
#pragma unroll
    for (int nf = 0; nf < 2; ++nf)
#pragma unroll
      for (int kk = 0; kk < 2; ++kk)
        bfr[nf][kk] = rdfrag(smB[1], wn * 32 + nf * 16 + frow, kk * 4 + a4);
    if (has2) {
      const size_t kA2 = (size_t)(base + 2) * 64;
      stage_half(Ag + kA2,                    smA[0],            w, lane);
      stage_half(Ag + (size_t)128 * KK + kA2, smA[0] + 128 * 64, w, lane);
    }
    PH_SYNC();
    __builtin_amdgcn_s_setprio(1);
#pragma unroll
    for (int f = 0; f < 4; ++f)
#pragma unroll
      for (int nf = 0; nf < 2; ++nf)
#pragma unroll
        for (int kk = 0; kk < 2; ++kk)
          acc[f][nf] = __builtin_amdgcn_mfma_f32_16x16x32_bf16(
              af[f][kk], bfr[nf][kk], acc[f][nf], 0, 0, 0);
    __builtin_amdgcn_s_setprio(0);
    __builtin_amdgcn_s_barrier();
    // ======== P4: kt1 A fr4-7; stage (base+3).B -> slot1; W2 = vmcnt(2)
#pragma unroll
    for (int f = 0; f < 4; ++f)
#pragma unroll
      for (int kk = 0; kk < 2; ++kk)
        af[f][kk] = rdfrag(smA[1], wm * 128 + (4 + f) * 16 + frow, kk * 4 + a4);
    if (has3) stage_half(Bg + (size_t)(base + 3) * 64, smB[1], w, lane);
    PH_SYNC();
    __builtin_amdgcn_s_setprio(1);
#pragma unroll
    for (int f = 0; f < 4; ++f)
#pragma unroll
      for (int nf = 0; nf < 2; ++nf)
#pragma unroll
        for (int kk = 0; kk < 2; ++kk)
          acc[4 + f][nf] = __builtin_amdgcn_mfma_f32_16x16x32_bf16(
              af[f][kk], bfr[nf][kk], acc[4 + f][nf], 0, 0, 0);
    __builtin_amdgcn_s_setprio(0);
    if (has2) {
      if (has3) { asm volatile("s_waitcnt vmcnt(2)" ::: "memory"); }
      else      { asm volatile("s_waitcnt vmcnt(0)" ::: "memory"); }
      __builtin_amdgcn_sched_barrier(0);
    }
    __builtin_amdgcn_s_barrier();
  }
  // ---- epilogue: per-wave rows [m0+wm*128,+128) x cols [n0+wn*32,+32)
  if (MODE == 0) {
    const int z = n0 >> 11;
    const float* bias = (z == 0) ? biasq : (z == 1) ? biask : biasv;
    bf16* o = (z == 0) ? Qo : (z == 1) ? Ko : Vo;
    const float oscale = (z == 1) ? (float)(0.08838834764831845 * 1.4426950408889634) : 1.0f;
#pragma unroll
    for (int nf = 0; nf < 2; ++nf) {
      const int col = n0 + wn * 32 + nf * 16 + frow;
      const float bb_ = bias[col & 2047];
      const int h = (col >> 7) & 15, hd = col & (Hd - 1);
#pragma unroll
      for (int mf = 0; mf < 8; ++mf) {
#pragma unroll
        for (int r = 0; r < 4; ++r) {
          const int row = m0 + wm * 128 + mf * 16 + a4 * 4 + r;
          const int bb = row >> 11, ss = row & (Ssz - 1);
          o[(((size_t)bb * NHd + h) * Ssz + ss) * Hd + hd] = (bf16)((acc[mf][nf][r] + bb_) * oscale);
        }
      }
    }
  } else {
#pragma unroll
    for (int mf = 0; mf < 8; ++mf)
#pragma unroll
      for (int nf = 0; nf < 2; ++nf) {
        const int col = n0 + wn * 32 + nf * 16 + frow;
#pragma unroll
        for (int r = 0; r < 4; ++r) {
          const int row = m0 + wm * 128 + mf * 16 + a4 * 4 + r;
          Fo[(size_t)row * Hid + col] = acc[mf][nf][r];
        }
      }
  }
}

// ---------------- RoPE (neox) on Q and K in place --------------------------
__global__ void k_rope(bf16* __restrict__ Q, bf16* __restrict__ Kk, const int* __restrict__ pos) {
  const int idx = blockIdx.x * 256 + threadIdx.x;   // (bh, s, i) i fastest
  const int i = idx & 63;
  const int s = (idx >> 6) & (Ssz - 1);
  const int bh = idx >> 17;
  const int b = bh >> 4;
  const float p = (float)pos[b * Ssz + s];
  const float f = p * exp2f(-(float)i * 0.20762050593046014f); // log2(1e4)/64
  float sn, cs;
  sincosf(f, &sn, &cs);
  const size_t base = ((size_t)bh * Ssz + s) * Hd;
  float x1 = (float)Q[base + i], x2 = (float)Q[base + i + 64];
  Q[base + i]      = (bf16)(x1 * cs - x2 * sn);
  Q[base + i + 64] = (bf16)(x2 * cs + x1 * sn);
  x1 = (float)Kk[base + i]; x2 = (float)Kk[base + i + 64];
  Kk[base + i]      = (bf16)(x1 * cs - x2 * sn);
  Kk[base + i + 64] = (bf16)(x2 * cs + x1 * sn);
}

// ------------- causal flash attention, swapped-QK, 32x32x16 MFMA -----------
// T14 async-stage: K(t+1) gload_lds + V(t+1)->reg issued before compute(t);
// double-buffered K/V LDS; counted vmcnt(8) before the compute barrier.
__global__ __launch_bounds__(256, 2) void k_attn(const bf16* __restrict__ Qg,
                                                 const bf16* __restrict__ Kg,
                                                 const bf16* __restrict__ Vg,
                                                 bf16* __restrict__ AO) {
  const int bh = blockIdx.y;
  int qc = blockIdx.x;
  if (bh & 1) qc = 15 - qc;            // causal load balance across co-resident blocks
  const int tid = threadIdx.x, lane = tid & 63, w = tid >> 6;
  const int l31 = lane & 31, h = lane >> 5;
  __shared__ bf16 Ks[2][64 * 128];     // XOR-swizzled contents (16B granule by row&7)
  __shared__ bf16 Vt[2][128 * 72];     // V^T: [hd][key], pad 72, swz by (hd>>3)&7
  const size_t hbase = (size_t)bh * Ssz * Hd;
  const int q0 = qc * 128 + w * 32;    // wave's first query row
  bf16x8 qf[8];
  {
    const bf16* qp = Qg + hbase + (size_t)(q0 + l31) * Hd + h * 8;
#pragma unroll
    for (int c = 0; c < 8; c++) qf[c] = *(const bf16x8*)(qp + c * 16);
  }
  float m = -1e30f, lsum = 0.f;
  f32x16 o[4] = {};
  const int NT = 2 * (qc + 1);
  const int r4  = (tid >> 4) << 2;     // V staging: this thread's 4 keys
  const int hd0 = (tid & 15) << 3;     //   and 8 hd values
  bf16x8 vv[4];
  // ---- prologue: issue tile-0 V->reg then K->LDS
#pragma unroll
  for (int p = 0; p < 4; p++)
    vv[p] = *(const bf16x8*)(Vg + hbase + (size_t)(r4 + p) * Hd + hd0);
  __builtin_amdgcn_sched_barrier(0);
#pragma unroll
  for (int i = 0; i < 4; i++) {
    const int db  = (w * 4 + i) * 1024 + (lane << 4);
    const int row = db >> 8;
    const int cb  = (db & 255) ^ ((row & 7) << 4);
    gload_lds16(Kg + hbase + row * Hd + (cb >> 1), Ks[0] + (w * 4 + i) * 512);
  }
  for (int t = 0; t < NT; ++t) {
    const int kv0 = t * 64;
    const int cur = t & 1;
    // ---- V(t) regs ready (oldest 4 of <=8 outstanding); write V(t) -> LDS
    asm volatile("s_waitcnt vmcnt(4)" ::: "memory");
#pragma unroll
    for (int j = 0; j < 8; j++) {
      uint2 wv;
      wv.x = pkbf(vv[0][j], vv[1][j]);
      wv.y = pkbf(vv[2][j], vv[3][j]);
      const int hd = hd0 + j;
      const int cb = (r4 * 2) ^ (((hd >> 3) & 7) << 4);
      *(uint2*)((char*)(Vt[cur]) + hd * 144 + cb) = wv;
    }
    // ---- issue tile t+1 (redundant re-issue of t on last iter)
    const int tn = (t + 1 < NT) ? t + 1 : t;
    const size_t nb = (size_t)tn * 64;
#pragma unroll
    for (int p = 0; p < 4; p++)
      vv[p] = *(const bf16x8*)(Vg + hbase + (nb + r4 + p) * Hd + hd0);
    __builtin_amdgcn_sched_barrier(0);
#pragma unroll
    for (int i = 0; i < 4; i++) {
      const int db  = (w * 4 + i) * 1024 + (lane << 4);
      const int row = db >> 8;
      const int cb  = (db & 255) ^ ((row & 7) << 4);
      gload_lds16(Kg + hbase + (nb + row) * Hd + (cb >> 1), Ks[cur ^ 1] + (w * 4 + i) * 512);
    }
    // ---- K(t) in LDS (8 newest = t+1's loads stay in flight); V writes visible
    asm volatile("s_waitcnt vmcnt(8) lgkmcnt(0)" ::: "memory");
    __builtin_amdgcn_sched_barrier(0);
    __builtin_amdgcn_s_barrier();
    if (kv0 <= q0 + 31) {              // wave-uniform: skip fully-masked tiles
      const bf16* KsC = Ks[cur];
      const bf16* VtC = Vt[cur];
      f32x16 s0 = {}, s1 = {};
#pragma unroll
      for (int c = 0; c < 8; c++) {
        const int cb = (c * 32 + h * 16) ^ ((l31 & 7) << 4);
        bf16x8 k0 = *(const bf16x8*)((const char*)KsC + l31 * 256 + cb);
        bf16x8 k1 = *(const bf16x8*)((const char*)KsC + (32 + l31) * 256 + cb);
        s0 = __builtin_amdgcn_mfma_f32_32x32x16_bf16(k0, qf[c], s0, 0, 0, 0);
        s1 = __builtin_amdgcn_mfma_f32_32x32x16_bf16(k1, qf[c], s1, 0, 0, 0);
      }
      if (kv0 + 63 > q0) {
        const int qg = q0 + l31;
        const int kb = kv0 + 4 * h;
#pragma unroll
        for (int r = 0; r < 16; r++) {
          const int cr = (r & 3) + 8 * (r >> 2);
          if (kb + cr > qg)      s0[r] = -1e30f;
          if (kb + 32 + cr > qg) s1[r] = -1e30f;
        }
      }
      float tm = s0[0];
#pragma unroll
      for (int r = 1; r < 16; r++) tm = fmaxf(tm, s0[r]);
#pragma unroll
      for (int r = 0; r < 16; r++) tm = fmaxf(tm, s1[r]);
      tm = fmaxf(tm, __shfl_xor(tm, 32));
      if (!__all(tm - m <= 8.0f)) {    // defer-max (T13)
        const float mn = fmaxf(m, tm);
        const float rs = exp2f(m - mn);
        m = mn; lsum *= rs;
#pragma unroll
        for (int ct = 0; ct < 4; ct++)
#pragma unroll
          for (int r = 0; r < 16; r++) o[ct][r] *= rs;
      }
      float ps = 0.f;
#pragma unroll
      for (int r = 0; r < 16; r++) { s0[r] = exp2f(s0[r] - m); ps += s0[r]; }
#pragma unroll
      for (int r = 0; r < 16; r++) { s1[r] = exp2f(s1[r] - m); ps += s1[r]; }
      ps += __shfl_xor(ps, 32);
      lsum += ps;
      uint32_t gw[8][2];
#pragma unroll
      for (int g = 0; g < 4; g++) {
        gw[g][0]     = pkff(s0[4 * g], s0[4 * g + 1]);
        gw[g][1]     = pkff(s0[4 * g + 2], s0[4 * g + 3]);
        gw[4 + g][0] = pkff(s1[4 * g], s1[4 * g + 1]);
        gw[4 + g][1] = pkff(s1[4 * g + 2], s1[4 * g + 3]);
      }
#pragma unroll
      for (int kc = 0; kc < 4; kc++) {
        const uint32_t a0 = gw[2 * kc][0], a1 = gw[2 * kc][1];
        const uint32_t b0 = gw[2 * kc + 1][0], b1 = gw[2 * kc + 1][1];
        const uint32_t sd0 = h ? a0 : b0, sd1 = h ? a1 : b1;
        const uint32_t r0 = (uint32_t)__shfl_xor((int)sd0, 32);
        const uint32_t r1 = (uint32_t)__shfl_xor((int)sd1, 32);
        union { uint32_t u[4]; bf16x8 v; } pa;
        pa.u[0] = h ? r0 : a0; pa.u[1] = h ? r1 : a1;
        pa.u[2] = h ? b0 : r0; pa.u[3] = h ? b1 : r1;
#pragma unroll
        for (int ct = 0; ct < 4; ct++) {
          const int row = ct * 32 + l31;
          const int cb = (kc * 32 + h * 16) ^ (((row >> 3) & 7) << 4);
          bf16x8 vf = *(const bf16x8*)((const char*)VtC + row * 144 + cb);
          o[ct] = __builtin_amdgcn_mfma_f32_32x32x16_bf16(pa.v, vf, o[ct], 0, 0, 0);
        }
      }
    }
    __builtin_amdgcn_s_barrier();      // compute done before next tile's writes
  }
  const float linv = 1.0f / lsum;
  float li[16];
#pragma unroll
  for (int r = 0; r < 16; r++)
    li[r] = __shfl(linv, (r & 3) + 8 * (r >> 2) + 4 * h);
  const int b = bh >> 4, hh = bh & 15;
#pragma unroll
  for (int ct = 0; ct < 4; ct++) {
#pragma unroll
    for (int r = 0; r < 16; r++) {
      const int qrow = q0 + (r & 3) + 8 * (r >> 2) + 4 * h;
      AO[((size_t)b * Ssz + qrow) * Hid + hh * Hd + ct * 32 + l31] = (bf16)(o[ct][r] * li[r]);
    }
  }
}

extern "C" void kernel_launch(void* const* d_in, const int* in_sizes, int n_in,
                              void* d_out, int out_size, void* d_ws, size_t ws_size,
                              hipStream_t stream) {
  (void)in_sizes; (void)n_in; (void)out_size; (void)ws_size;
  const float* hidden   = (const float*)d_in[0];
  const int*   positions= (const int*)d_in[1];
  const float* wq = (const float*)d_in[2];
  const float* bq = (const float*)d_in[3];
  const float* wk = (const float*)d_in[4];
  const float* bk = (const float*)d_in[5];
  const float* wv = (const float*)d_in[6];
  const float* bv = (const float*)d_in[7];
  const float* wc = (const float*)d_in[8];
  float* out = (float*)d_out;

  char* ws = (char*)d_ws;
  bf16* WT  = (bf16*)ws;                                               // 4*Hid*Hid bf16 (q,k,v,c)
  bf16* Hbf = (bf16*)(ws + (size_t)4 * Hid * Hid * 2);                 // Mrows*Hid (reused as AO)
  bf16* Qb  = (bf16*)(ws + (size_t)4 * Hid * Hid * 2 + (size_t)Mrows * Hid * 2);
  bf16* Kb  = Qb + (size_t)Mrows * Hid;
  bf16* Vb  = Kb + (size_t)Mrows * Hid;

  k_cvt<<<dim3(Mrows * Hid / 4 / 256), dim3(256), 0, stream>>>(hidden, Hbf, Mrows * Hid / 4);
  k_wtrans<<<dim3(Hid / 32, Hid / 32, 4), dim3(32, 8), 0, stream>>>(wq, wk, wv, wc, WT);
  // fused QKV: N = 6144, grid 48x16 = 768 blocks = 3.0 exact CU-rounds
  k_gemm<0, 8, 12><<<dim3(48, 16), dim3(512), 0, stream>>>(
      Hbf, WT, bq, bk, bv, Qb, Kb, Vb, nullptr);
  k_rope<<<dim3(Bsz * NHd * Ssz * 64 / 256), dim3(256), 0, stream>>>(Qb, Kb, positions);
  k_attn<<<dim3(16, Bsz * NHd), dim3(256), 0, stream>>>(Qb, Kb, Vb, Hbf /*AO*/);
  // output projection: grid 16x16 = 256 blocks = 1.0 exact CU-round
  k_gemm<1, 8, 4><<<dim3(16, 16), dim3(512), 0, stream>>>(
      Hbf, WT + (size_t)3 * Hid * Hid, nullptr, nullptr, nullptr,
      nullptr, nullptr, nullptr, out);
}

// Round 7
// 282.661 us; speedup vs baseline: 1.1718x; 1.0542x over previous
//
#include <hip/hip_runtime.h>
#include <stdint.h>

constexpr int Bsz = 2;
constexpr int Ssz = 2048;
constexpr int Hid = 2048;
constexpr int NHd = 16;
constexpr int Hd  = 128;
constexpr int Mrows = Bsz * Ssz;                 // 4096

typedef __bf16 bf16;
typedef __bf16 bf16x8 __attribute__((ext_vector_type(8)));
typedef __bf16 bf16x4 __attribute__((ext_vector_type(4)));
typedef float  f32x4  __attribute__((ext_vector_type(4)));
typedef float  f32x16 __attribute__((ext_vector_type(16)));

__device__ __forceinline__ void gload_lds16(const bf16* g, bf16* l) {
  __builtin_amdgcn_global_load_lds((const __attribute__((address_space(1))) void*)g,
                                   (__attribute__((address_space(3))) void*)l, 16, 0, 0);
}

__device__ __forceinline__ uint32_t pkbf(bf16 a, bf16 b) {
  union { bf16 hh[2]; uint32_t u; } x;
  x.hh[0] = a; x.hh[1] = b;
  return x.u;
}
__device__ __forceinline__ uint32_t pkff(float a, float b) {
  return pkbf((bf16)a, (bf16)b);
}

// ---------------- f32 -> bf16 bulk convert (4 elems/thread) ----------------
__global__ void k_cvt(const float* __restrict__ in, bf16* __restrict__ out, int n4) {
  int i = blockIdx.x * blockDim.x + threadIdx.x;
  if (i >= n4) return;
  float4 v = ((const float4*)in)[i];
  bf16x4 o = { (bf16)v.x, (bf16)v.y, (bf16)v.z, (bf16)v.w };
  ((bf16x4*)out)[i] = o;
}

// ------------- transpose 4 weights [K][N] f32 -> [N][K] bf16 ---------------
__global__ void k_wtrans(const float* __restrict__ w0, const float* __restrict__ w1,
                         const float* __restrict__ w2, const float* __restrict__ w3,
                         bf16* __restrict__ out) {
  __shared__ float tile[32][33];
  int z = blockIdx.z;
  const float* w = (z == 0) ? w0 : (z == 1) ? w1 : (z == 2) ? w2 : w3;
  bf16* o = out + (size_t)z * Hid * Hid;
  int n0 = blockIdx.x * 32, k0 = blockIdx.y * 32;
  int tx = threadIdx.x, ty = threadIdx.y;
#pragma unroll
  for (int i = 0; i < 4; i++)
    tile[ty + i * 8][tx] = w[(size_t)(k0 + ty + i * 8) * Hid + n0 + tx];
  __syncthreads();
#pragma unroll
  for (int i = 0; i < 4; i++)
    o[(size_t)(n0 + ty + i * 8) * Hid + k0 + tx] = (bf16)tile[tx][ty + i * 8];
}

// ---- swizzled-LDS fragment read: element (row,k) lives at byte
//      row*128 + (((k>>3) ^ (row&7))<<4) + (k&7)*2
__device__ __forceinline__ bf16x8 rdfrag(const bf16* t, int row, int kslot) {
  return *(const bf16x8*)((const char*)t + row * 128 + (((kslot ^ (row & 7)) & 7) << 4));
}

// ---- stage a 128-row x 64-col bf16 slice (16 KB) into linear LDS,
//      source pre-inverse-swizzled so reads use rdfrag (rule #21).
//      2 gload_lds per thread (8 waves x 2 x 1KB = 16 KB).
__device__ __forceinline__ void stage_half(const bf16* g, bf16* l, int w, int lane) {
  const int rsub = lane >> 3;
  const int slot = (lane & 7) ^ rsub;
#pragma unroll
  for (int j = 0; j < 2; ++j) {
    const int blk = w * 2 + j;
    gload_lds16(g + (size_t)(blk * 8 + rsub) * Hid + slot * 8, l + blk * 512);
  }
}

// ---- stage a 192-row x 64-col slice (24 KB): 3 gload_lds per thread
__device__ __forceinline__ void stage_192(const bf16* g, bf16* l, int w, int lane) {
  const int rsub = lane >> 3;
  const int slot = (lane & 7) ^ rsub;
#pragma unroll
  for (int j = 0; j < 3; ++j) {
    const int blk = w * 3 + j;
    gload_lds16(g + (size_t)(blk * 8 + rsub) * Hid + slot * 8, l + blk * 512);
  }
}

#define PH_SYNC()                                      \
  __builtin_amdgcn_s_barrier();                        \
  asm volatile("s_waitcnt lgkmcnt(0)" ::: "memory");   \
  __builtin_amdgcn_sched_barrier(0);

// ---- QKV GEMM, m201-style fine phases: 256x192 tile, BK=64, 8 waves
//      (2m x 4n), per-wave 128x48, 3 phases/K-tile x 16 MFMA (P3 reg-only),
//      dbuf 112 KB LDS, boundary wait covers loads issued >=1 phase earlier.
//      C = A@W^T + bias -> bf16 scatter [b][h][s][hd]; K scaled kScale*log2e.
__global__ __launch_bounds__(512, 1) void k_qkv(const bf16* __restrict__ A,
                                                const bf16* __restrict__ Bt,
                                                const float* __restrict__ biasq,
                                                const float* __restrict__ biask,
                                                const float* __restrict__ biasv,
                                                bf16* __restrict__ Qo, bf16* __restrict__ Ko,
                                                bf16* __restrict__ Vo) {
  constexpr int KK = Hid;
  constexpr int NT = KK / 64;          // 32 K-tiles
  __shared__ bf16 smA[2][256 * 64];    // 64 KB
  __shared__ bf16 smB[2][192 * 64];    // 48 KB
  // T1: grid 32n x 16m = 512 blocks; chunks 8m x 8n (2 x 4), bijective
  const int hw = blockIdx.y * gridDim.x + blockIdx.x;
  const int chunk = hw & 7, within = hw >> 3;
  const int cr = chunk & 1, cc = chunk >> 1;
  const int mt = cr * 8 + (within & 7);
  const int nt = cc * 8 + (within >> 3);
  const int m0 = mt * 256, n0 = nt * 192;
  const int tid = threadIdx.x, lane = tid & 63, w = tid >> 6;
  const int wm = w >> 2, wn = w & 3;
  const int frow = lane & 15, a4 = lane >> 4;
  const bf16* Ag = A + (size_t)m0 * KK;
  const bf16* Bg = Bt + (size_t)n0 * KK;
  f32x4 acc[8][3] = {};
  // ---- prologue: tile 0 -> slot 0
  stage_half(Ag,                    smA[0],            w, lane);
  stage_half(Ag + (size_t)128 * KK, smA[0] + 128 * 64, w, lane);
  stage_192 (Bg,                    smB[0],            w, lane);
  asm volatile("s_waitcnt vmcnt(0)" ::: "memory");
  __builtin_amdgcn_s_barrier();
  for (int kt = 0; kt < NT; ++kt) {
    const bf16* At  = smA[kt & 1];
    const bf16* Btl = smB[kt & 1];
    bf16* As2 = smA[(kt + 1) & 1];
    bf16* Bs2 = smB[(kt + 1) & 1];
    const bool more = (kt + 1) < NT;
    const size_t kn = (size_t)(kt + 1) * 64;
    bf16x8 afA[4][2], afB[4][2], bfr[3][2];
    // ======== P1: A rows 0-63 (8 ds) + all B (6 ds); stage next A (4 gloads)
#pragma unroll
    for (int f = 0; f < 4; ++f)
#pragma unroll
      for (int kk = 0; kk < 2; ++kk)
        afA[f][kk] = rdfrag(At, wm * 128 + f * 16 + frow, kk * 4 + a4);
#pragma unroll
    for (int nf = 0; nf < 3; ++nf)
#pragma unroll
      for (int kk = 0; kk < 2; ++kk)
        bfr[nf][kk] = rdfrag(Btl, wn * 48 + nf * 16 + frow, kk * 4 + a4);
    if (more) {
      stage_half(Ag + kn,                    As2,            w, lane);
      stage_half(Ag + (size_t)128 * KK + kn, As2 + 128 * 64, w, lane);
    }
    PH_SYNC();
    __builtin_amdgcn_s_setprio(1);
#pragma unroll
    for (int f = 0; f < 4; ++f)
#pragma unroll
      for (int nf = 0; nf < 2; ++nf)
#pragma unroll
        for (int kk = 0; kk < 2; ++kk)
          acc[f][nf] = __builtin_amdgcn_mfma_f32_16x16x32_bf16(
              afA[f][kk], bfr[nf][kk], acc[f][nf], 0, 0, 0);
    __builtin_amdgcn_s_setprio(0);
    __builtin_amdgcn_s_barrier();
    // ======== P2: A rows 64-127 (8 ds); stage next B (3 gloads)
#pragma unroll
    for (int f = 0; f < 4; ++f)
#pragma unroll
      for (int kk = 0; kk < 2; ++kk)
        afB[f][kk] = rdfrag(At, wm * 128 + 64 + f * 16 + frow, kk * 4 + a4);
    if (more) stage_192(Bg + kn, Bs2, w, lane);
    PH_SYNC();
    __builtin_amdgcn_s_setprio(1);
#pragma unroll
    for (int f = 0; f < 4; ++f)
#pragma unroll
      for (int nf = 0; nf < 2; ++nf)
#pragma unroll
        for (int kk = 0; kk < 2; ++kk)
          acc[4 + f][nf] = __builtin_amdgcn_mfma_f32_16x16x32_bf16(
              afB[f][kk], bfr[nf][kk], acc[4 + f][nf], 0, 0, 0);
    __builtin_amdgcn_s_setprio(0);
    __builtin_amdgcn_s_barrier();
    // ======== P3 (register-only): nf2 column for all 8 m-frags; then boundary
    __builtin_amdgcn_s_setprio(1);
#pragma unroll
    for (int f = 0; f < 4; ++f)
#pragma unroll
      for (int kk = 0; kk < 2; ++kk)
        acc[f][2] = __builtin_amdgcn_mfma_f32_16x16x32_bf16(
            afA[f][kk], bfr[2][kk], acc[f][2], 0, 0, 0);
#pragma unroll
    for (int f = 0; f < 4; ++f)
#pragma unroll
      for (int kk = 0; kk < 2; ++kk)
        acc[4 + f][2] = __builtin_amdgcn_mfma_f32_16x16x32_bf16(
            afB[f][kk], bfr[2][kk], acc[4 + f][2], 0, 0, 0);
    __builtin_amdgcn_s_setprio(0);
    asm volatile("s_waitcnt vmcnt(0)" ::: "memory");   // loads >=1 phase old
    __builtin_amdgcn_sched_barrier(0);
    __builtin_amdgcn_s_barrier();
  }
  // ---- epilogue: per-column z (192-wide tiles straddle q/k/v boundaries)
#pragma unroll
  for (int nf = 0; nf < 3; ++nf) {
    const int col = n0 + wn * 48 + nf * 16 + frow;
    const int z = col >> 11;
    const float* bias = (z == 0) ? biasq : (z == 1) ? biask : biasv;
    bf16* o = (z == 0) ? Qo : (z == 1) ? Ko : Vo;
    const float oscale = (z == 1) ? (float)(0.08838834764831845 * 1.4426950408889634) : 1.0f;
    const float bb_ = bias[col & 2047];
    const int h = (col >> 7) & 15, hd = col & (Hd - 1);
#pragma unroll
    for (int mf = 0; mf < 8; ++mf) {
#pragma unroll
      for (int r = 0; r < 4; ++r) {
        const int row = m0 + wm * 128 + mf * 16 + a4 * 4 + r;
        const int bb = row >> 11, ss = row & (Ssz - 1);
        o[(((size_t)bb * NHd + h) * Ssz + ss) * Hd + hd] = (bf16)((acc[mf][nf][r] + bb_) * oscale);
      }
    }
  }
}

// ---- output-projection GEMM (R6 structure, proven): 256x128, BK=64, 8 waves,
//      per-wave 128x32, 4 phases / 2 K-tiles, counted vmcnt(2), 96 KB LDS.
template <int CHM, int CHN>
__global__ __launch_bounds__(512, 1) void k_gemm(const bf16* __restrict__ A,
                                                 const bf16* __restrict__ Bt,
                                                 float* __restrict__ Fo) {
  constexpr int KK = Hid;
  constexpr int NT = KK / 64;
  __shared__ bf16 smA[2][256 * 64];
  __shared__ bf16 smB[2][128 * 64];
  const int hw = blockIdx.y * gridDim.x + blockIdx.x;
  const int chunk = hw & 7, within = hw >> 3;
  const int chunk_rows = gridDim.y / CHM;
  const int cr = chunk % chunk_rows, cc = chunk / chunk_rows;
  const int mt = cr * CHM + within % CHM;
  const int nt = cc * CHN + within / CHM;
  const int m0 = mt * 256, n0 = nt * 128;
  const int tid = threadIdx.x, lane = tid & 63, w = tid >> 6;
  const int wm = w >> 2, wn = w & 3;
  const int frow = lane & 15, a4 = lane >> 4;
  const bf16* Ag = A + (size_t)m0 * KK;
  const bf16* Bg = Bt + (size_t)n0 * KK;
  f32x4 acc[8][2] = {};
  stage_half(Ag,                    smA[0],            w, lane);
  stage_half(Ag + (size_t)128 * KK, smA[0] + 128 * 64, w, lane);
  stage_half(Bg,                    smB[0],            w, lane);
  stage_half(Bg + 64,               smB[1],            w, lane);
  asm volatile("s_waitcnt vmcnt(2)" ::: "memory");
  __builtin_amdgcn_sched_barrier(0);
  __builtin_amdgcn_s_barrier();
  for (int it = 0; it < NT / 2; ++it) {
    const int base = 2 * it;
    const bool has2 = (base + 2) < NT;
    const bool has3 = (base + 3) < NT;
    bf16x8 af[4][2], bfr[2][2];
#pragma unroll
    for (int f = 0; f < 4; ++f)
#pragma unroll
      for (int kk = 0; kk < 2; ++kk)
        af[f][kk] = rdfrag(smA[0], wm * 128 + f * 16 + frow, kk * 4 + a4);
#pragma unroll
    for (int nf = 0; nf < 2; ++nf)
#pragma unroll
      for (int kk = 0; kk < 2; ++kk)
        bfr[nf][kk] = rdfrag(smB[0], wn * 32 + nf * 16 + frow, kk * 4 + a4);
    {
      const size_t kA1 = (size_t)(base + 1) * 64;
      stage_half(Ag + kA1,                    smA[1],            w, lane);
      stage_half(Ag + (size_t)128 * KK + kA1, smA[1] + 128 * 64, w, lane);
    }
    PH_SYNC();
    __builtin_amdgcn_s_setprio(1);
#pragma unroll
    for (int f = 0; f < 4; ++f)
#pragma unroll
      for (int nf = 0; nf < 2; ++nf)
#pragma unroll
        for (int kk = 0; kk < 2; ++kk)
          acc[f][nf] = __builtin_amdgcn_mfma_f32_16x16x32_bf16(
              af[f][kk], bfr[nf][kk], acc[f][nf], 0, 0, 0);
    __builtin_amdgcn_s_setprio(0);
    __builtin_amdgcn_s_barrier();
#pragma unroll
    for (int f = 0; f < 4; ++f)
#pragma unroll
      for (int kk = 0; kk < 2; ++kk)
        af[f][kk] = rdfrag(smA[0], wm * 128 + (4 + f) * 16 + frow, kk * 4 + a4);
    if (has2) stage_half(Bg + (size_t)(base + 2) * 64, smB[0], w, lane);
    PH_SYNC();
    __builtin_amdgcn_s_setprio(1);
#pragma unroll
    for (int f = 0; f < 4; ++f)
#pragma unroll
      for (int nf = 0; nf < 2; ++nf)
#pragma unroll
        for (int kk = 0; kk < 2; ++kk)
          acc[4 + f][nf] = __builtin_amdgcn_mfma_f32_16x16x32_bf16(
              af[f][kk], bfr[nf][kk], acc[4 + f][nf], 0, 0, 0);
    __builtin_amdgcn_s_setprio(0);
    if (has2) { asm volatile("s_waitcnt vmcnt(2)" ::: "memory"); }
    else      { asm volatile("s_waitcnt vmcnt(0)" ::: "memory"); }
    __builtin_amdgcn_sched_barrier(0);
    __builtin_amdgcn_s_barrier();
#pragma unroll
    for (int f = 0; f < 4; ++f)
#pragma unroll
      for (int kk = 0; kk < 2; ++kk)
        af[f][kk] = rdfrag(smA[1], wm * 128 + f * 16 + frow, kk * 4 + a4);
#pragma unroll
    for (int nf = 0; nf < 2; ++nf)
#pragma unroll
      for (int kk = 0; kk < 2; ++kk)
        bfr[nf][kk] = rdfrag(smB[1], wn * 32 + nf * 16 + frow, kk * 4 + a4);
    if (has2) {
      const size_t kA2 = (size_t)(base + 2) * 64;
      stage_half(Ag + kA2,                    smA[0],            w, lane);
      stage_half(Ag + (size_t)128 * KK + kA2, smA[0] + 128 * 64, w, lane);
    }
    PH_SYNC();
    __builtin_amdgcn_s_setprio(1);
#pragma unroll
    for (int f = 0; f < 4; ++f)
#pragma unroll
      for (int nf = 0; nf < 2; ++nf)
#pragma unroll
        for (int kk = 0; kk < 2; ++kk)
          acc[f][nf] = __builtin_amdgcn_mfma_f32_16x16x32_bf16(
              af[f][kk], bfr[nf][kk], acc[f][nf], 0, 0, 0);
    __builtin_amdgcn_s_setprio(0);
    __builtin_amdgcn_s_barrier();
#pragma unroll
    for (int f = 0; f < 4; ++f)
#pragma unroll
      for (int kk = 0; kk < 2; ++kk)
        af[f][kk] = rdfrag(smA[1], wm * 128 + (4 + f) * 16 + frow, kk * 4 + a4);
    if (has3) stage_half(Bg + (size_t)(base + 3) * 64, smB[1], w, lane);
    PH_SYNC();
    __builtin_amdgcn_s_setprio(1);
#pragma unroll
    for (int f = 0; f < 4; ++f)
#pragma unroll
      for (int nf = 0; nf < 2; ++nf)
#pragma unroll
        for (int kk = 0; kk < 2; ++kk)
          acc[4 + f][nf] = __builtin_amdgcn_mfma_f32_16x16x32_bf16(
              af[f][kk], bfr[nf][kk], acc[4 + f][nf], 0, 0, 0);
    __builtin_amdgcn_s_setprio(0);
    if (has2) {
      if (has3) { asm volatile("s_waitcnt vmcnt(2)" ::: "memory"); }
      else      { asm volatile("s_waitcnt vmcnt(0)" ::: "memory"); }
      __builtin_amdgcn_sched_barrier(0);
    }
    __builtin_amdgcn_s_barrier();
  }
#pragma unroll
  for (int mf = 0; mf < 8; ++mf)
#pragma unroll
    for (int nf = 0; nf < 2; ++nf) {
      const int col = n0 + wn * 32 + nf * 16 + frow;
#pragma unroll
      for (int r = 0; r < 4; ++r) {
        const int row = m0 + wm * 128 + mf * 16 + a4 * 4 + r;
        Fo[(size_t)row * Hid + col] = acc[mf][nf][r];
      }
    }
}

// ---------------- RoPE (neox) on Q and K in place --------------------------
__global__ void k_rope(bf16* __restrict__ Q, bf16* __restrict__ Kk, const int* __restrict__ pos) {
  const int idx = blockIdx.x * 256 + threadIdx.x;   // (bh, s, i) i fastest
  const int i = idx & 63;
  const int s = (idx >> 6) & (Ssz - 1);
  const int bh = idx >> 17;
  const int b = bh >> 4;
  const float p = (float)pos[b * Ssz + s];
  const float f = p * exp2f(-(float)i * 0.20762050593046014f); // log2(1e4)/64
  float sn, cs;
  sincosf(f, &sn, &cs);
  const size_t base = ((size_t)bh * Ssz + s) * Hd;
  float x1 = (float)Q[base + i], x2 = (float)Q[base + i + 64];
  Q[base + i]      = (bf16)(x1 * cs - x2 * sn);
  Q[base + i + 64] = (bf16)(x2 * cs + x1 * sn);
  x1 = (float)Kk[base + i]; x2 = (float)Kk[base + i + 64];
  Kk[base + i]      = (bf16)(x1 * cs - x2 * sn);
  Kk[base + i + 64] = (bf16)(x2 * cs + x1 * sn);
}

// ------------- causal flash attention, swapped-QK, 32x32x16 MFMA -----------
__global__ __launch_bounds__(256, 2) void k_attn(const bf16* __restrict__ Qg,
                                                 const bf16* __restrict__ Kg,
                                                 const bf16* __restrict__ Vg,
                                                 bf16* __restrict__ AO) {
  const int bh = blockIdx.y;
  int qc = blockIdx.x;
  if (bh & 1) qc = 15 - qc;            // causal load balance across co-resident blocks
  const int tid = threadIdx.x, lane = tid & 63, w = tid >> 6;
  const int l31 = lane & 31, h = lane >> 5;
  __shared__ bf16 Ks[2][64 * 128];     // XOR-swizzled contents (16B granule by row&7)
  __shared__ bf16 Vt[2][128 * 72];     // V^T: [hd][key], pad 72, swz by (hd>>3)&7
  const size_t hbase = (size_t)bh * Ssz * Hd;
  const int q0 = qc * 128 + w * 32;    // wave's first query row
  bf16x8 qf[8];
  {
    const bf16* qp = Qg + hbase + (size_t)(q0 + l31) * Hd + h * 8;
#pragma unroll
    for (int c = 0; c < 8; c++) qf[c] = *(const bf16x8*)(qp + c * 16);
  }
  float m = -1e30f, lsum = 0.f;
  f32x16 o[4] = {};
  const int NT = 2 * (qc + 1);
  const int r4  = (tid >> 4) << 2;     // V staging: this thread's 4 keys
  const int hd0 = (tid & 15) << 3;     //   and 8 hd values
  bf16x8 vv[4];
#pragma unroll
  for (int p = 0; p < 4; p++)
    vv[p] = *(const bf16x8*)(Vg + hbase + (size_t)(r4 + p) * Hd + hd0);
  __builtin_amdgcn_sched_barrier(0);
#pragma unroll
  for (int i = 0; i < 4; i++) {
    const int db  = (w * 4 + i) * 1024 + (lane << 4);
    const int row = db >> 8;
    const int cb  = (db & 255) ^ ((row & 7) << 4);
    gload_lds16(Kg + hbase + row * Hd + (cb >> 1), Ks[0] + (w * 4 + i) * 512);
  }
  for (int t = 0; t < NT; ++t) {
    const int kv0 = t * 64;
    const int cur = t & 1;
    asm volatile("s_waitcnt vmcnt(4)" ::: "memory");
#pragma unroll
    for (int j = 0; j < 8; j++) {
      uint2 wv;
      wv.x = pkbf(vv[0][j], vv[1][j]);
      wv.y = pkbf(vv[2][j], vv[3][j]);
      const int hd = hd0 + j;
      const int cb = (r4 * 2) ^ (((hd >> 3) & 7) << 4);
      *(uint2*)((char*)(Vt[cur]) + hd * 144 + cb) = wv;
    }
    const int tn = (t + 1 < NT) ? t + 1 : t;
    const size_t nb = (size_t)tn * 64;
#pragma unroll
    for (int p = 0; p < 4; p++)
      vv[p] = *(const bf16x8*)(Vg + hbase + (nb + r4 + p) * Hd + hd0);
    __builtin_amdgcn_sched_barrier(0);
#pragma unroll
    for (int i = 0; i < 4; i++) {
      const int db  = (w * 4 + i) * 1024 + (lane << 4);
      const int row = db >> 8;
      const int cb  = (db & 255) ^ ((row & 7) << 4);
      gload_lds16(Kg + hbase + (nb + row) * Hd + (cb >> 1), Ks[cur ^ 1] + (w * 4 + i) * 512);
    }
    asm volatile("s_waitcnt vmcnt(8) lgkmcnt(0)" ::: "memory");
    __builtin_amdgcn_sched_barrier(0);
    __builtin_amdgcn_s_barrier();
    if (kv0 <= q0 + 31) {
      const bf16* KsC = Ks[cur];
      const bf16* VtC = Vt[cur];
      f32x16 s0 = {}, s1 = {};
#pragma unroll
      for (int c = 0; c < 8; c++) {
        const int cb = (c * 32 + h * 16) ^ ((l31 & 7) << 4);
        bf16x8 k0 = *(const bf16x8*)((const char*)KsC + l31 * 256 + cb);
        bf16x8 k1 = *(const bf16x8*)((const char*)KsC + (32 + l31) * 256 + cb);
        s0 = __builtin_amdgcn_mfma_f32_32x32x16_bf16(k0, qf[c], s0, 0, 0, 0);
        s1 = __builtin_amdgcn_mfma_f32_32x32x16_bf16(k1, qf[c], s1, 0, 0, 0);
      }
      if (kv0 + 63 > q0) {
        const int qg = q0 + l31;
        const int kb = kv0 + 4 * h;
#pragma unroll
        for (int r = 0; r < 16; r++) {
          const int cr = (r & 3) + 8 * (r >> 2);
          if (kb + cr > qg)      s0[r] = -1e30f;
          if (kb + 32 + cr > qg) s1[r] = -1e30f;
        }
      }
      float tm = s0[0];
#pragma unroll
      for (int r = 1; r < 16; r++) tm = fmaxf(tm, s0[r]);
#pragma unroll
      for (int r = 0; r < 16; r++) tm = fmaxf(tm, s1[r]);
      tm = fmaxf(tm, __shfl_xor(tm, 32));
      if (!__all(tm - m <= 8.0f)) {
        const float mn = fmaxf(m, tm);
        const float rs = exp2f(m - mn);
        m = mn; lsum *= rs;
#pragma unroll
        for (int ct = 0; ct < 4; ct++)
#pragma unroll
          for (int r = 0; r < 16; r++) o[ct][r] *= rs;
      }
      float ps = 0.f;
#pragma unroll
      for (int r = 0; r < 16; r++) { s0[r] = exp2f(s0[r] - m); ps += s0[r]; }
#pragma unroll
      for (int r = 0; r < 16; r++) { s1[r] = exp2f(s1[r] - m); ps += s1[r]; }
      ps += __shfl_xor(ps, 32);
      lsum += ps;
      uint32_t gw[8][2];
#pragma unroll
      for (int g = 0; g < 4; g++) {
        gw[g][0]     = pkff(s0[4 * g], s0[4 * g + 1]);
        gw[g][1]     = pkff(s0[4 * g + 2], s0[4 * g + 3]);
        gw[4 + g][0] = pkff(s1[4 * g], s1[4 * g + 1]);
        gw[4 + g][1] = pkff(s1[4 * g + 2], s1[4 * g + 3]);
      }
#pragma unroll
      for (int kc = 0; kc < 4; kc++) {
        const uint32_t a0 = gw[2 * kc][0], a1 = gw[2 * kc][1];
        const uint32_t b0 = gw[2 * kc + 1][0], b1 = gw[2 * kc + 1][1];
        const uint32_t sd0 = h ? a0 : b0, sd1 = h ? a1 : b1;
        const uint32_t r0 = (uint32_t)__shfl_xor((int)sd0, 32);
        const uint32_t r1 = (uint32_t)__shfl_xor((int)sd1, 32);
        union { uint32_t u[4]; bf16x8 v; } pa;
        pa.u[0] = h ? r0 : a0; pa.u[1] = h ? r1 : a1;
        pa.u[2] = h ? b0 : r0; pa.u[3] = h ? b1 : r1;
#pragma unroll
        for (int ct = 0; ct < 4; ct++) {
          const int row = ct * 32 + l31;
          const int cb = (kc * 32 + h * 16) ^ (((row >> 3) & 7) << 4);
          bf16x8 vf = *(const bf16x8*)((const char*)VtC + row * 144 + cb);
          o[ct] = __builtin_amdgcn_mfma_f32_32x32x16_bf16(pa.v, vf, o[ct], 0, 0, 0);
        }
      }
    }
    __builtin_amdgcn_s_barrier();
  }
  const float linv = 1.0f / lsum;
  float li[16];
#pragma unroll
  for (int r = 0; r < 16; r++)
    li[r] = __shfl(linv, (r & 3) + 8 * (r >> 2) + 4 * h);
  const int b = bh >> 4, hh = bh & 15;
#pragma unroll
  for (int ct = 0; ct < 4; ct++) {
#pragma unroll
    for (int r = 0; r < 16; r++) {
      const int qrow = q0 + (r & 3) + 8 * (r >> 2) + 4 * h;
      AO[((size_t)b * Ssz + qrow) * Hid + hh * Hd + ct * 32 + l31] = (bf16)(o[ct][r] * li[r]);
    }
  }
}

extern "C" void kernel_launch(void* const* d_in, const int* in_sizes, int n_in,
                              void* d_out, int out_size, void* d_ws, size_t ws_size,
                              hipStream_t stream) {
  (void)in_sizes; (void)n_in; (void)out_size; (void)ws_size;
  const float* hidden   = (const float*)d_in[0];
  const int*   positions= (const int*)d_in[1];
  const float* wq = (const float*)d_in[2];
  const float* bq = (const float*)d_in[3];
  const float* wk = (const float*)d_in[4];
  const float* bk = (const float*)d_in[5];
  const float* wv = (const float*)d_in[6];
  const float* bv = (const float*)d_in[7];
  const float* wc = (const float*)d_in[8];
  float* out = (float*)d_out;

  char* ws = (char*)d_ws;
  bf16* WT  = (bf16*)ws;                                               // 4*Hid*Hid bf16 (q,k,v,c)
  bf16* Hbf = (bf16*)(ws + (size_t)4 * Hid * Hid * 2);                 // Mrows*Hid (reused as AO)
  bf16* Qb  = (bf16*)(ws + (size_t)4 * Hid * Hid * 2 + (size_t)Mrows * Hid * 2);
  bf16* Kb  = Qb + (size_t)Mrows * Hid;
  bf16* Vb  = Kb + (size_t)Mrows * Hid;

  k_cvt<<<dim3(Mrows * Hid / 4 / 256), dim3(256), 0, stream>>>(hidden, Hbf, Mrows * Hid / 4);
  k_wtrans<<<dim3(Hid / 32, Hid / 32, 4), dim3(32, 8), 0, stream>>>(wq, wk, wv, wc, WT);
  // fused QKV: 256x192 tiles, grid 32n x 16m = 512 blocks = 2.0 exact rounds
  k_qkv<<<dim3(32, 16), dim3(512), 0, stream>>>(
      Hbf, WT, bq, bk, bv, Qb, Kb, Vb);
  k_rope<<<dim3(Bsz * NHd * Ssz * 64 / 256), dim3(256), 0, stream>>>(Qb, Kb, positions);
  k_attn<<<dim3(16, Bsz * NHd), dim3(256), 0, stream>>>(Qb, Kb, Vb, Hbf /*AO*/);
  // output projection: grid 16x16 = 256 blocks = 1.0 exact CU-round
  k_gemm<8, 4><<<dim3(16, 16), dim3(512), 0, stream>>>(
      Hbf, WT + (size_t)3 * Hid * Hid, out);
}

// Round 8
// 261.378 us; speedup vs baseline: 1.2673x; 1.0814x over previous
//
#include <hip/hip_runtime.h>
#include <stdint.h>

constexpr int Bsz = 2;
constexpr int Ssz = 2048;
constexpr int Hid = 2048;
constexpr int NHd = 16;
constexpr int Hd  = 128;
constexpr int Mrows = Bsz * Ssz;                 // 4096

typedef __bf16 bf16;
typedef __bf16 bf16x8 __attribute__((ext_vector_type(8)));
typedef __bf16 bf16x4 __attribute__((ext_vector_type(4)));
typedef float  f32x4  __attribute__((ext_vector_type(4)));
typedef float  f32x16 __attribute__((ext_vector_type(16)));

__device__ __forceinline__ void gload_lds16(const bf16* g, bf16* l) {
  __builtin_amdgcn_global_load_lds((const __attribute__((address_space(1))) void*)g,
                                   (__attribute__((address_space(3))) void*)l, 16, 0, 0);
}

__device__ __forceinline__ uint32_t pkbf(bf16 a, bf16 b) {
  union { bf16 hh[2]; uint32_t u; } x;
  x.hh[0] = a; x.hh[1] = b;
  return x.u;
}
__device__ __forceinline__ uint32_t pkff(float a, float b) {
  return pkbf((bf16)a, (bf16)b);
}

// ---------------- f32 -> bf16 bulk convert (4 elems/thread) ----------------
__global__ void k_cvt(const float* __restrict__ in, bf16* __restrict__ out, int n4) {
  int i = blockIdx.x * blockDim.x + threadIdx.x;
  if (i >= n4) return;
  float4 v = ((const float4*)in)[i];
  bf16x4 o = { (bf16)v.x, (bf16)v.y, (bf16)v.z, (bf16)v.w };
  ((bf16x4*)out)[i] = o;
}

// ------------- transpose 4 weights [K][N] f32 -> [N][K] bf16 ---------------
__global__ void k_wtrans(const float* __restrict__ w0, const float* __restrict__ w1,
                         const float* __restrict__ w2, const float* __restrict__ w3,
                         bf16* __restrict__ out) {
  __shared__ float tile[32][33];
  int z = blockIdx.z;
  const float* w = (z == 0) ? w0 : (z == 1) ? w1 : (z == 2) ? w2 : w3;
  bf16* o = out + (size_t)z * Hid * Hid;
  int n0 = blockIdx.x * 32, k0 = blockIdx.y * 32;
  int tx = threadIdx.x, ty = threadIdx.y;
#pragma unroll
  for (int i = 0; i < 4; i++)
    tile[ty + i * 8][tx] = w[(size_t)(k0 + ty + i * 8) * Hid + n0 + tx];
  __syncthreads();
#pragma unroll
  for (int i = 0; i < 4; i++)
    o[(size_t)(n0 + ty + i * 8) * Hid + k0 + tx] = (bf16)tile[tx][ty + i * 8];
}

// ---- swizzled-LDS fragment read: element (row,k) lives at byte
//      row*128 + (((k>>3) ^ (row&7))<<4) + (k&7)*2
__device__ __forceinline__ bf16x8 rdfrag(const bf16* t, int row, int kslot) {
  return *(const bf16x8*)((const char*)t + row * 128 + (((kslot ^ (row & 7)) & 7) << 4));
}

// ---- stage a 128-row x 64-col bf16 slice (16 KB) into linear LDS,
//      source pre-inverse-swizzled so reads use rdfrag (rule #21).
__device__ __forceinline__ void stage_half(const bf16* g, bf16* l, int w, int lane) {
  const int rsub = lane >> 3;
  const int slot = (lane & 7) ^ rsub;
#pragma unroll
  for (int j = 0; j < 2; ++j) {
    const int blk = w * 2 + j;
    gload_lds16(g + (size_t)(blk * 8 + rsub) * Hid + slot * 8, l + blk * 512);
  }
}

// ---- stage a 192-row x 64-col slice (24 KB): 3 gload_lds per thread
__device__ __forceinline__ void stage_192(const bf16* g, bf16* l, int w, int lane) {
  const int rsub = lane >> 3;
  const int slot = (lane & 7) ^ rsub;
#pragma unroll
  for (int j = 0; j < 3; ++j) {
    const int blk = w * 3 + j;
    gload_lds16(g + (size_t)(blk * 8 + rsub) * Hid + slot * 8, l + blk * 512);
  }
}

#define PH_SYNC()                                      \
  __builtin_amdgcn_s_barrier();                        \
  asm volatile("s_waitcnt lgkmcnt(0)" ::: "memory");   \
  __builtin_amdgcn_sched_barrier(0);

// ---- QKV GEMM, m201-style fine phases: 256x192 tile, BK=64, 8 waves
//      (2m x 4n), per-wave 128x48, 3 phases/K-tile x 16 MFMA (P3 reg-only).
__global__ __launch_bounds__(512, 1) void k_qkv(const bf16* __restrict__ A,
                                                const bf16* __restrict__ Bt,
                                                const float* __restrict__ biasq,
                                                const float* __restrict__ biask,
                                                const float* __restrict__ biasv,
                                                bf16* __restrict__ Qo, bf16* __restrict__ Ko,
                                                bf16* __restrict__ Vo) {
  constexpr int KK = Hid;
  constexpr int NT = KK / 64;          // 32 K-tiles
  __shared__ bf16 smA[2][256 * 64];    // 64 KB
  __shared__ bf16 smB[2][192 * 64];    // 48 KB
  const int hw = blockIdx.y * gridDim.x + blockIdx.x;
  const int chunk = hw & 7, within = hw >> 3;
  const int cr = chunk & 1, cc = chunk >> 1;
  const int mt = cr * 8 + (within & 7);
  const int nt = cc * 8 + (within >> 3);
  const int m0 = mt * 256, n0 = nt * 192;
  const int tid = threadIdx.x, lane = tid & 63, w = tid >> 6;
  const int wm = w >> 2, wn = w & 3;
  const int frow = lane & 15, a4 = lane >> 4;
  const bf16* Ag = A + (size_t)m0 * KK;
  const bf16* Bg = Bt + (size_t)n0 * KK;
  f32x4 acc[8][3] = {};
  stage_half(Ag,                    smA[0],            w, lane);
  stage_half(Ag + (size_t)128 * KK, smA[0] + 128 * 64, w, lane);
  stage_192 (Bg,                    smB[0],            w, lane);
  asm volatile("s_waitcnt vmcnt(0)" ::: "memory");
  __builtin_amdgcn_s_barrier();
  for (int kt = 0; kt < NT; ++kt) {
    const bf16* At  = smA[kt & 1];
    const bf16* Btl = smB[kt & 1];
    bf16* As2 = smA[(kt + 1) & 1];
    bf16* Bs2 = smB[(kt + 1) & 1];
    const bool more = (kt + 1) < NT;
    const size_t kn = (size_t)(kt + 1) * 64;
    bf16x8 afA[4][2], afB[4][2], bfr[3][2];
#pragma unroll
    for (int f = 0; f < 4; ++f)
#pragma unroll
      for (int kk = 0; kk < 2; ++kk)
        afA[f][kk] = rdfrag(At, wm * 128 + f * 16 + frow, kk * 4 + a4);
#pragma unroll
    for (int nf = 0; nf < 3; ++nf)
#pragma unroll
      for (int kk = 0; kk < 2; ++kk)
        bfr[nf][kk] = rdfrag(Btl, wn * 48 + nf * 16 + frow, kk * 4 + a4);
    if (more) {
      stage_half(Ag + kn,                    As2,            w, lane);
      stage_half(Ag + (size_t)128 * KK + kn, As2 + 128 * 64, w, lane);
    }
    PH_SYNC();
    __builtin_amdgcn_s_setprio(1);
#pragma unroll
    for (int f = 0; f < 4; ++f)
#pragma unroll
      for (int nf = 0; nf < 2; ++nf)
#pragma unroll
        for (int kk = 0; kk < 2; ++kk)
          acc[f][nf] = __builtin_amdgcn_mfma_f32_16x16x32_bf16(
              afA[f][kk], bfr[nf][kk], acc[f][nf], 0, 0, 0);
    __builtin_amdgcn_s_setprio(0);
    __builtin_amdgcn_s_barrier();
#pragma unroll
    for (int f = 0; f < 4; ++f)
#pragma unroll
      for (int kk = 0; kk < 2; ++kk)
        afB[f][kk] = rdfrag(At, wm * 128 + 64 + f * 16 + frow, kk * 4 + a4);
    if (more) stage_192(Bg + kn, Bs2, w, lane);
    PH_SYNC();
    __builtin_amdgcn_s_setprio(1);
#pragma unroll
    for (int f = 0; f < 4; ++f)
#pragma unroll
      for (int nf = 0; nf < 2; ++nf)
#pragma unroll
        for (int kk = 0; kk < 2; ++kk)
          acc[4 + f][nf] = __builtin_amdgcn_mfma_f32_16x16x32_bf16(
              afB[f][kk], bfr[nf][kk], acc[4 + f][nf], 0, 0, 0);
    __builtin_amdgcn_s_setprio(0);
    __builtin_amdgcn_s_barrier();
    __builtin_amdgcn_s_setprio(1);
#pragma unroll
    for (int f = 0; f < 4; ++f)
#pragma unroll
      for (int kk = 0; kk < 2; ++kk)
        acc[f][2] = __builtin_amdgcn_mfma_f32_16x16x32_bf16(
            afA[f][kk], bfr[2][kk], acc[f][2], 0, 0, 0);
#pragma unroll
    for (int f = 0; f < 4; ++f)
#pragma unroll
      for (int kk = 0; kk < 2; ++kk)
        acc[4 + f][2] = __builtin_amdgcn_mfma_f32_16x16x32_bf16(
            afB[f][kk], bfr[2][kk], acc[4 + f][2], 0, 0, 0);
    __builtin_amdgcn_s_setprio(0);
    asm volatile("s_waitcnt vmcnt(0)" ::: "memory");
    __builtin_amdgcn_sched_barrier(0);
    __builtin_amdgcn_s_barrier();
  }
#pragma unroll
  for (int nf = 0; nf < 3; ++nf) {
    const int col = n0 + wn * 48 + nf * 16 + frow;
    const int z = col >> 11;
    const float* bias = (z == 0) ? biasq : (z == 1) ? biask : biasv;
    bf16* o = (z == 0) ? Qo : (z == 1) ? Ko : Vo;
    const float oscale = (z == 1) ? (float)(0.08838834764831845 * 1.4426950408889634) : 1.0f;
    const float bb_ = bias[col & 2047];
    const int h = (col >> 7) & 15, hd = col & (Hd - 1);
#pragma unroll
    for (int mf = 0; mf < 8; ++mf) {
#pragma unroll
      for (int r = 0; r < 4; ++r) {
        const int row = m0 + wm * 128 + mf * 16 + a4 * 4 + r;
        const int bb = row >> 11, ss = row & (Ssz - 1);
        o[(((size_t)bb * NHd + h) * Ssz + ss) * Hd + hd] = (bf16)((acc[mf][nf][r] + bb_) * oscale);
      }
    }
  }
}

// ---- output-projection GEMM (R6 structure): 256x128, BK=64, 8 waves,
//      per-wave 128x32, 4 phases / 2 K-tiles, counted vmcnt(2), 96 KB LDS.
template <int CHM, int CHN>
__global__ __launch_bounds__(512, 1) void k_gemm(const bf16* __restrict__ A,
                                                 const bf16* __restrict__ Bt,
                                                 float* __restrict__ Fo) {
  constexpr int KK = Hid;
  constexpr int NT = KK / 64;
  __shared__ bf16 smA[2][256 * 64];
  __shared__ bf16 smB[2][128 * 64];
  const int hw = blockIdx.y * gridDim.x + blockIdx.x;
  const int chunk = hw & 7, within = hw >> 3;
  const int chunk_rows = gridDim.y / CHM;
  const int cr = chunk % chunk_rows, cc = chunk / chunk_rows;
  const int mt = cr * CHM + within % CHM;
  const int nt = cc * CHN + within / CHM;
  const int m0 = mt * 256, n0 = nt * 128;
  const int tid = threadIdx.x, lane = tid & 63, w = tid >> 6;
  const int wm = w >> 2, wn = w & 3;
  const int frow = lane & 15, a4 = lane >> 4;
  const bf16* Ag = A + (size_t)m0 * KK;
  const bf16* Bg = Bt + (size_t)n0 * KK;
  f32x4 acc[8][2] = {};
  stage_half(Ag,                    smA[0],            w, lane);
  stage_half(Ag + (size_t)128 * KK, smA[0] + 128 * 64, w, lane);
  stage_half(Bg,                    smB[0],            w, lane);
  stage_half(Bg + 64,               smB[1],            w, lane);
  asm volatile("s_waitcnt vmcnt(2)" ::: "memory");
  __builtin_amdgcn_sched_barrier(0);
  __builtin_amdgcn_s_barrier();
  for (int it = 0; it < NT / 2; ++it) {
    const int base = 2 * it;
    const bool has2 = (base + 2) < NT;
    const bool has3 = (base + 3) < NT;
    bf16x8 af[4][2], bfr[2][2];
#pragma unroll
    for (int f = 0; f < 4; ++f)
#pragma unroll
      for (int kk = 0; kk < 2; ++kk)
        af[f][kk] = rdfrag(smA[0], wm * 128 + f * 16 + frow, kk * 4 + a4);
#pragma unroll
    for (int nf = 0; nf < 2; ++nf)
#pragma unroll
      for (int kk = 0; kk < 2; ++kk)
        bfr[nf][kk] = rdfrag(smB[0], wn * 32 + nf * 16 + frow, kk * 4 + a4);
    {
      const size_t kA1 = (size_t)(base + 1) * 64;
      stage_half(Ag + kA1,                    smA[1],            w, lane);
      stage_half(Ag + (size_t)128 * KK + kA1, smA[1] + 128 * 64, w, lane);
    }
    PH_SYNC();
    __builtin_amdgcn_s_setprio(1);
#pragma unroll
    for (int f = 0; f < 4; ++f)
#pragma unroll
      for (int nf = 0; nf < 2; ++nf)
#pragma unroll
        for (int kk = 0; kk < 2; ++kk)
          acc[f][nf] = __builtin_amdgcn_mfma_f32_16x16x32_bf16(
              af[f][kk], bfr[nf][kk], acc[f][nf], 0, 0, 0);
    __builtin_amdgcn_s_setprio(0);
    __builtin_amdgcn_s_barrier();
#pragma unroll
    for (int f = 0; f < 4; ++f)
#pragma unroll
      for (int kk = 0; kk < 2; ++kk)
        af[f][kk] = rdfrag(smA[0], wm * 128 + (4 + f) * 16 + frow, kk * 4 + a4);
    if (has2) stage_half(Bg + (size_t)(base + 2) * 64, smB[0], w, lane);
    PH_SYNC();
    __builtin_amdgcn_s_setprio(1);
#pragma unroll
    for (int f = 0; f < 4; ++f)
#pragma unroll
      for (int nf = 0; nf < 2; ++nf)
#pragma unroll
        for (int kk = 0; kk < 2; ++kk)
          acc[4 + f][nf] = __builtin_amdgcn_mfma_f32_16x16x32_bf16(
              af[f][kk], bfr[nf][kk], acc[4 + f][nf], 0, 0, 0);
    __builtin_amdgcn_s_setprio(0);
    if (has2) { asm volatile("s_waitcnt vmcnt(2)" ::: "memory"); }
    else      { asm volatile("s_waitcnt vmcnt(0)" ::: "memory"); }
    __builtin_amdgcn_sched_barrier(0);
    __builtin_amdgcn_s_barrier();
#pragma unroll
    for (int f = 0; f < 4; ++f)
#pragma unroll
      for (int kk = 0; kk < 2; ++kk)
        af[f][kk] = rdfrag(smA[1], wm * 128 + f * 16 + frow, kk * 4 + a4);
#pragma unroll
    for (int nf = 0; nf < 2; ++nf)
#pragma unroll
      for (int kk = 0; kk < 2; ++kk)
        bfr[nf][kk] = rdfrag(smB[1], wn * 32 + nf * 16 + frow, kk * 4 + a4);
    if (has2) {
      const size_t kA2 = (size_t)(base + 2) * 64;
      stage_half(Ag + kA2,                    smA[0],            w, lane);
      stage_half(Ag + (size_t)128 * KK + kA2, smA[0] + 128 * 64, w, lane);
    }
    PH_SYNC();
    __builtin_amdgcn_s_setprio(1);
#pragma unroll
    for (int f = 0; f < 4; ++f)
#pragma unroll
      for (int nf = 0; nf < 2; ++nf)
#pragma unroll
        for (int kk = 0; kk < 2; ++kk)
          acc[f][nf] = __builtin_amdgcn_mfma_f32_16x16x32_bf16(
              af[f][kk], bfr[nf][kk], acc[f][nf], 0, 0, 0);
    __builtin_amdgcn_s_setprio(0);
    __builtin_amdgcn_s_barrier();
#pragma unroll
    for (int f = 0; f < 4; ++f)
#pragma unroll
      for (int kk = 0; kk < 2; ++kk)
        af[f][kk] = rdfrag(smA[1], wm * 128 + (4 + f) * 16 + frow, kk * 4 + a4);
    if (has3) stage_half(Bg + (size_t)(base + 3) * 64, smB[1], w, lane);
    PH_SYNC();
    __builtin_amdgcn_s_setprio(1);
#pragma unroll
    for (int f = 0; f < 4; ++f)
#pragma unroll
      for (int nf = 0; nf < 2; ++nf)
#pragma unroll
        for (int kk = 0; kk < 2; ++kk)
          acc[4 + f][nf] = __builtin_amdgcn_mfma_f32_16x16x32_bf16(
              af[f][kk], bfr[nf][kk], acc[4 + f][nf], 0, 0, 0);
    __builtin_amdgcn_s_setprio(0);
    if (has2) {
      if (has3) { asm volatile("s_waitcnt vmcnt(2)" ::: "memory"); }
      else      { asm volatile("s_waitcnt vmcnt(0)" ::: "memory"); }
      __builtin_amdgcn_sched_barrier(0);
    }
    __builtin_amdgcn_s_barrier();
  }
#pragma unroll
  for (int mf = 0; mf < 8; ++mf)
#pragma unroll
    for (int nf = 0; nf < 2; ++nf) {
      const int col = n0 + wn * 32 + nf * 16 + frow;
#pragma unroll
      for (int r = 0; r < 4; ++r) {
        const int row = m0 + wm * 128 + mf * 16 + a4 * 4 + r;
        Fo[(size_t)row * Hid + col] = acc[mf][nf][r];
      }
    }
}

// ---------------- RoPE (neox) on Q and K in place --------------------------
__global__ void k_rope(bf16* __restrict__ Q, bf16* __restrict__ Kk, const int* __restrict__ pos) {
  const int idx = blockIdx.x * 256 + threadIdx.x;   // (bh, s, i) i fastest
  const int i = idx & 63;
  const int s = (idx >> 6) & (Ssz - 1);
  const int bh = idx >> 17;
  const int b = bh >> 4;
  const float p = (float)pos[b * Ssz + s];
  const float f = p * exp2f(-(float)i * 0.20762050593046014f); // log2(1e4)/64
  float sn, cs;
  sincosf(f, &sn, &cs);
  const size_t base = ((size_t)bh * Ssz + s) * Hd;
  float x1 = (float)Q[base + i], x2 = (float)Q[base + i + 64];
  Q[base + i]      = (bf16)(x1 * cs - x2 * sn);
  Q[base + i + 64] = (bf16)(x2 * cs + x1 * sn);
  x1 = (float)Kk[base + i]; x2 = (float)Kk[base + i + 64];
  Kk[base + i]      = (bf16)(x1 * cs - x2 * sn);
  Kk[base + i + 64] = (bf16)(x2 * cs + x1 * sn);
}

// ------------- causal flash attention, swapped-QK, 32x32x16 MFMA -----------
// Balanced 1D grid: co-resident pair (bid, bid+256) gets complementary qc
// (x, 15-x) -> every CU does exactly 34 kv-tile units. XCD = bh&7 (L2-local).
__global__ __launch_bounds__(256, 2) void k_attn(const bf16* __restrict__ Qg,
                                                 const bf16* __restrict__ Kg,
                                                 const bf16* __restrict__ Vg,
                                                 bf16* __restrict__ AO) {
  const int bid = blockIdx.x;
  const int slot = bid & 255;
  const int bh = slot & 31;
  const int xch = slot >> 5;
  const int qc = (bid >> 8) ? (15 - xch) : xch;
  const int tid = threadIdx.x, lane = tid & 63, w = tid >> 6;
  const int l31 = lane & 31, h = lane >> 5;
  __shared__ bf16 Ks[2][64 * 128];     // XOR-swizzled contents (16B granule by row&7)
  __shared__ bf16 Vt[2][128 * 72];     // V^T: [hd][key], pad 72, swz by (hd>>3)&7
  const size_t hbase = (size_t)bh * Ssz * Hd;
  const int q0 = qc * 128 + w * 32;    // wave's first query row
  bf16x8 qf[8];
  {
    const bf16* qp = Qg + hbase + (size_t)(q0 + l31) * Hd + h * 8;
#pragma unroll
    for (int c = 0; c < 8; c++) qf[c] = *(const bf16x8*)(qp + c * 16);
  }
  float m = -1e30f, lsum = 0.f;
  f32x16 o[4] = {};
  const int NT = 2 * (qc + 1);
  const int r4  = (tid >> 4) << 2;     // V staging: this thread's 4 keys
  const int hd0 = (tid & 15) << 3;     //   and 8 hd values
  bf16x8 vv[4];
#pragma unroll
  for (int p = 0; p < 4; p++)
    vv[p] = *(const bf16x8*)(Vg + hbase + (size_t)(r4 + p) * Hd + hd0);
  __builtin_amdgcn_sched_barrier(0);
#pragma unroll
  for (int i = 0; i < 4; i++) {
    const int db  = (w * 4 + i) * 1024 + (lane << 4);
    const int row = db >> 8;
    const int cb  = (db & 255) ^ ((row & 7) << 4);
    gload_lds16(Kg + hbase + row * Hd + (cb >> 1), Ks[0] + (w * 4 + i) * 512);
  }
  for (int t = 0; t < NT; ++t) {
    const int kv0 = t * 64;
    const int cur = t & 1;
    asm volatile("s_waitcnt vmcnt(4)" ::: "memory");
#pragma unroll
    for (int j = 0; j < 8; j++) {
      uint2 wv;
      wv.x = pkbf(vv[0][j], vv[1][j]);
      wv.y = pkbf(vv[2][j], vv[3][j]);
      const int hd = hd0 + j;
      const int cb = (r4 * 2) ^ (((hd >> 3) & 7) << 4);
      *(uint2*)((char*)(Vt[cur]) + hd * 144 + cb) = wv;
    }
    const int tn = (t + 1 < NT) ? t + 1 : t;
    const size_t nb = (size_t)tn * 64;
#pragma unroll
    for (int p = 0; p < 4; p++)
      vv[p] = *(const bf16x8*)(Vg + hbase + (nb + r4 + p) * Hd + hd0);
    __builtin_amdgcn_sched_barrier(0);
#pragma unroll
    for (int i = 0; i < 4; i++) {
      const int db  = (w * 4 + i) * 1024 + (lane << 4);
      const int row = db >> 8;
      const int cb  = (db & 255) ^ ((row & 7) << 4);
      gload_lds16(Kg + hbase + (nb + row) * Hd + (cb >> 1), Ks[cur ^ 1] + (w * 4 + i) * 512);
    }
    asm volatile("s_waitcnt vmcnt(8) lgkmcnt(0)" ::: "memory");
    __builtin_amdgcn_sched_barrier(0);
    __builtin_amdgcn_s_barrier();
    if (kv0 <= q0 + 31) {
      const bf16* KsC = Ks[cur];
      const bf16* VtC = Vt[cur];
      f32x16 s0 = {}, s1 = {};
      __builtin_amdgcn_s_setprio(1);
#pragma unroll
      for (int c = 0; c < 8; c++) {
        const int cb = (c * 32 + h * 16) ^ ((l31 & 7) << 4);
        bf16x8 k0 = *(const bf16x8*)((const char*)KsC + l31 * 256 + cb);
        bf16x8 k1 = *(const bf16x8*)((const char*)KsC + (32 + l31) * 256 + cb);
        s0 = __builtin_amdgcn_mfma_f32_32x32x16_bf16(k0, qf[c], s0, 0, 0, 0);
        s1 = __builtin_amdgcn_mfma_f32_32x32x16_bf16(k1, qf[c], s1, 0, 0, 0);
      }
      __builtin_amdgcn_s_setprio(0);
      if (kv0 + 63 > q0) {
        const int qg = q0 + l31;
        const int kb = kv0 + 4 * h;
#pragma unroll
        for (int r = 0; r < 16; r++) {
          const int cr = (r & 3) + 8 * (r >> 2);
          if (kb + cr > qg)      s0[r] = -1e30f;
          if (kb + 32 + cr > qg) s1[r] = -1e30f;
        }
      }
      float tm = s0[0];
#pragma unroll
      for (int r = 1; r < 16; r++) tm = fmaxf(tm, s0[r]);
#pragma unroll
      for (int r = 0; r < 16; r++) tm = fmaxf(tm, s1[r]);
      tm = fmaxf(tm, __shfl_xor(tm, 32));
      if (!__all(tm - m <= 8.0f)) {
        const float mn = fmaxf(m, tm);
        const float rs = exp2f(m - mn);
        m = mn; lsum *= rs;
#pragma unroll
        for (int ct = 0; ct < 4; ct++)
#pragma unroll
          for (int r = 0; r < 16; r++) o[ct][r] *= rs;
      }
      float ps = 0.f;
#pragma unroll
      for (int r = 0; r < 16; r++) { s0[r] = exp2f(s0[r] - m); ps += s0[r]; }
#pragma unroll
      for (int r = 0; r < 16; r++) { s1[r] = exp2f(s1[r] - m); ps += s1[r]; }
      ps += __shfl_xor(ps, 32);
      lsum += ps;
      uint32_t gw[8][2];
#pragma unroll
      for (int g = 0; g < 4; g++) {
        gw[g][0]     = pkff(s0[4 * g], s0[4 * g + 1]);
        gw[g][1]     = pkff(s0[4 * g + 2], s0[4 * g + 3]);
        gw[4 + g][0] = pkff(s1[4 * g], s1[4 * g + 1]);
        gw[4 + g][1] = pkff(s1[4 * g + 2], s1[4 * g + 3]);
      }
#pragma unroll
      for (int kc = 0; kc < 4; kc++) {
        const uint32_t a0 = gw[2 * kc][0], a1 = gw[2 * kc][1];
        const uint32_t b0 = gw[2 * kc + 1][0], b1 = gw[2 * kc + 1][1];
        const uint32_t sd0 = h ? a0 : b0, sd1 = h ? a1 : b1;
        const uint32_t r0 = (uint32_t)__shfl_xor((int)sd0, 32);
        const uint32_t r1 = (uint32_t)__shfl_xor((int)sd1, 32);
        union { uint32_t u[4]; bf16x8 v; } pa;
        pa.u[0] = h ? r0 : a0; pa.u[1] = h ? r1 : a1;
        pa.u[2] = h ? b0 : r0; pa.u[3] = h ? b1 : r1;
        __builtin_amdgcn_s_setprio(1);
#pragma unroll
        for (int ct = 0; ct < 4; ct++) {
          const int row = ct * 32 + l31;
          const int cb = (kc * 32 + h * 16) ^ (((row >> 3) & 7) << 4);
          bf16x8 vf = *(const bf16x8*)((const char*)VtC + row * 144 + cb);
          o[ct] = __builtin_amdgcn_mfma_f32_32x32x16_bf16(pa.v, vf, o[ct], 0, 0, 0);
        }
        __builtin_amdgcn_s_setprio(0);
      }
    }
    __builtin_amdgcn_s_barrier();
  }
  const float linv = 1.0f / lsum;
  float li[16];
#pragma unroll
  for (int r = 0; r < 16; r++)
    li[r] = __shfl(linv, (r & 3) + 8 * (r >> 2) + 4 * h);
  const int b = bh >> 4, hh = bh & 15;
#pragma unroll
  for (int ct = 0; ct < 4; ct++) {
#pragma unroll
    for (int r = 0; r < 16; r++) {
      const int qrow = q0 + (r & 3) + 8 * (r >> 2) + 4 * h;
      AO[((size_t)b * Ssz + qrow) * Hid + hh * Hd + ct * 32 + l31] = (bf16)(o[ct][r] * li[r]);
    }
  }
}

extern "C" void kernel_launch(void* const* d_in, const int* in_sizes, int n_in,
                              void* d_out, int out_size, void* d_ws, size_t ws_size,
                              hipStream_t stream) {
  (void)in_sizes; (void)n_in; (void)out_size; (void)ws_size;
  const float* hidden   = (const float*)d_in[0];
  const int*   positions= (const int*)d_in[1];
  const float* wq = (const float*)d_in[2];
  const float* bq = (const float*)d_in[3];
  const float* wk = (const float*)d_in[4];
  const float* bk = (const float*)d_in[5];
  const float* wv = (const float*)d_in[6];
  const float* bv = (const float*)d_in[7];
  const float* wc = (const float*)d_in[8];
  float* out = (float*)d_out;

  char* ws = (char*)d_ws;
  bf16* WT  = (bf16*)ws;                                               // 4*Hid*Hid bf16 (q,k,v,c)
  bf16* Hbf = (bf16*)(ws + (size_t)4 * Hid * Hid * 2);                 // Mrows*Hid (reused as AO)
  bf16* Qb  = (bf16*)(ws + (size_t)4 * Hid * Hid * 2 + (size_t)Mrows * Hid * 2);
  bf16* Kb  = Qb + (size_t)Mrows * Hid;
  bf16* Vb  = Kb + (size_t)Mrows * Hid;

  k_cvt<<<dim3(Mrows * Hid / 4 / 256), dim3(256), 0, stream>>>(hidden, Hbf, Mrows * Hid / 4);
  k_wtrans<<<dim3(Hid / 32, Hid / 32, 4), dim3(32, 8), 0, stream>>>(wq, wk, wv, wc, WT);
  // fused QKV: 256x192 tiles, grid 32n x 16m = 512 blocks = 2.0 exact rounds
  k_qkv<<<dim3(32, 16), dim3(512), 0, stream>>>(
      Hbf, WT, bq, bk, bv, Qb, Kb, Vb);
  k_rope<<<dim3(Bsz * NHd * Ssz * 64 / 256), dim3(256), 0, stream>>>(Qb, Kb, positions);
  // balanced 1D attention grid: pair (bid, bid+256) is (x, 15-x)
  k_attn<<<dim3(512), dim3(256), 0, stream>>>(Qb, Kb, Vb, Hbf /*AO*/);
  // output projection: grid 16x16 = 256 blocks = 1.0 exact CU-round
  k_gemm<8, 4><<<dim3(16, 16), dim3(512), 0, stream>>>(
      Hbf, WT + (size_t)3 * Hid * Hid, out);
}